// Round 10
// baseline (2170.127 us; speedup 1.0000x reference)
//
#include <hip/hip_runtime.h>
#include <stdint.h>

typedef short short8 __attribute__((ext_vector_type(8)));
typedef float f32x4 __attribute__((ext_vector_type(4)));
typedef float f32x16 __attribute__((ext_vector_type(16)));

#define N_NODES 500
#define HGC 16
#define DH 512
#define T_STEPS 64
#define NB 32
#define F_IN 8
#define DSTEPS 16
#define E_EDGES 16000
#define E_TOT 16500
#define NH 8000          // N*HG
#define G3 1536          // 3*D
#define BT 2048          // B*T
#define DKC 10           // decoder K-split (800 K each = 50 nodes)
#define DNT 48           // decoder ntiles (32 cols each)
#define DBLK 480         // 48 x 10 blocks

__device__ __forceinline__ unsigned short f2bf(float x) {
  unsigned int u = __float_as_uint(x);
  u = (u + 0x7fffu + ((u >> 16) & 1u)) >> 16;
  return (unsigned short)u;
}

__device__ __forceinline__ void gl_lds16(const void* g, void* l) {
  __builtin_amdgcn_global_load_lds((const __attribute__((address_space(1))) void*)g,
                                   (__attribute__((address_space(3))) void*)l, 16, 0, 0);
}

__device__ __forceinline__ float sigm(float x) { return 1.f / (1.f + __expf(-x)); }

// ---------------- fused graph prep (1 block, 512 threads) ----------------
__global__ __launch_bounds__(512) void k_graph(const int* __restrict__ ei,
                                               int* __restrict__ rowptr,
                                               int* __restrict__ colg, float* __restrict__ nrmg) {
  __shared__ int degL[512];
  __shared__ int scanL[512];
  __shared__ int curL[512];
  __shared__ float dinvL[512];
  int t = threadIdx.x;
  degL[t] = (t < N_NODES) ? 1 : 0;
  __syncthreads();
  for (int e = t; e < E_EDGES; e += 512) atomicAdd(&degL[ei[E_EDGES + e]], 1);
  __syncthreads();
  int v = degL[t];
  scanL[t] = v;
  __syncthreads();
  for (int off = 1; off < 512; off <<= 1) {
    int add = (t >= off) ? scanL[t - off] : 0;
    __syncthreads();
    scanL[t] += add;
    __syncthreads();
  }
  int excl = scanL[t] - v;
  if (t < N_NODES) {
    rowptr[t] = excl;
    curL[t] = excl;
    dinvL[t] = rsqrtf((float)v);
  }
  if (t == 0) rowptr[N_NODES] = scanL[511];
  __syncthreads();
  for (int e = t; e < E_TOT; e += 512) {
    int s_, d_;
    if (e < E_EDGES) { s_ = ei[e]; d_ = ei[E_EDGES + e]; }
    else { s_ = d_ = e - E_EDGES; }
    int pos = atomicAdd(&curL[d_], 1);
    colg[pos] = s_;
    nrmg[pos] = dinvL[s_] * dinvL[d_];
  }
}

// ---------------- merged f32 -> bf16 bulk convert (3 tensors) ----------------
__global__ void k_f2bf_all(const float* __restrict__ a, unsigned short* __restrict__ da, int n4a,
                           const float* __restrict__ b, unsigned short* __restrict__ db, int n4b,
                           const float* __restrict__ c, unsigned short* __restrict__ dc, int n4c) {
  int i = blockIdx.x * blockDim.x + threadIdx.x;
  const float* s;
  unsigned short* d;
  int j = i;
  if (j < n4a) { s = a; d = da; }
  else {
    j -= n4a;
    if (j < n4b) { s = b; d = db; }
    else {
      j -= n4b;
      if (j >= n4c) return;
      s = c; d = dc;
    }
  }
  float4 v = ((const float4*)s)[j];
  ushort4 o;
  o.x = f2bf(v.x); o.y = f2bf(v.y); o.z = f2bf(v.z); o.w = f2bf(v.w);
  ((ushort4*)d)[j] = o;
}

// ---------------- repack dWih f32 -> per-block blobs (bf16), layout [nd][kg][col][8] ----------------
__global__ __launch_bounds__(256) void k_repack(const float* __restrict__ dWih,
                                                unsigned short* __restrict__ wihDp) {
  int i = blockIdx.x * 256 + threadIdx.x;   // 768000 total
  if (i >= DBLK * 50 * 32) return;
  int blob = i / 1600, r = i - blob * 1600;
  int nd = r >> 5, col = r & 31;
  int ntile = blob / DKC, kc = blob - ntile * DKC;
  const float* src = dWih + (size_t)(ntile * 32 + col) * NH + kc * 800 + nd * 16;
  short8 lo, hi;
#pragma unroll
  for (int c = 0; c < 8; ++c) {
    lo[c] = (short)f2bf(src[c]);
    hi[c] = (short)f2bf(src[c + 8]);
  }
  unsigned short* dst = wihDp + (size_t)blob * 25600 + nd * 512 + col * 8;
  *(short8*)dst = lo;
  *(short8*)(dst + 256) = hi;
}

// ---------------- x (2048,500,8) f32 -> xT2 (16384, 512) bf16 (zero-padded cols) ----------------
__global__ __launch_bounds__(256) void k_transpose(const float* __restrict__ x,
                                                   unsigned short* __restrict__ xT2) {
  __shared__ float xs[N_NODES * 9];
  int g = blockIdx.x, t = threadIdx.x;
  const float4* xg = (const float4*)(x + (size_t)g * (N_NODES * F_IN));
  for (int i = t; i < N_NODES * 2; i += 256) {
    float4 v = xg[i];
    int n = i >> 1, fh = (i & 1) * 4;
    float* d = &xs[n * 9 + fh];
    d[0] = v.x; d[1] = v.y; d[2] = v.z; d[3] = v.w;
  }
  __syncthreads();
  int f = t >> 5, u = t & 31;
  short8 lo, hi;
#pragma unroll
  for (int j = 0; j < 8; ++j) {
    int n0 = u * 16 + j, n1 = n0 + 8;
    lo[j] = (short)((n0 < N_NODES) ? f2bf(xs[n0 * 9 + f]) : 0);
    hi[j] = (short)((n1 < N_NODES) ? f2bf(xs[n1 * 9 + f]) : 0);
  }
  unsigned short* dst = xT2 + (size_t)(g * 8 + f) * 512 + u * 16;
  *(short8*)dst = lo;
  *(short8*)(dst + 8) = hi;
}

// ---------------- densify Ahat rows (by dst) -> (512, 512) bf16 ----------------
__global__ __launch_bounds__(256) void k_densify(const int* __restrict__ rowptr,
                                                 const int* __restrict__ col,
                                                 const float* __restrict__ nrm,
                                                 unsigned short* __restrict__ AhatD) {
  __shared__ float row[512];
  int n = blockIdx.x, t = threadIdx.x;
  row[t] = 0.f; row[t + 256] = 0.f;
  __syncthreads();
  if (n < N_NODES) {
    int e1 = rowptr[n + 1];
    for (int e = rowptr[n] + t; e < e1; e += 256) atomicAdd(&row[col[e]], nrm[e]);
  }
  __syncthreads();
  AhatD[n * 512 + t] = f2bf(row[t]);
  AhatD[n * 512 + t + 256] = f2bf(row[t + 256]);
}

// ---------------- agg GEMM: C(16384 gf, 512 n) = xT2 . AhatD^T ; fused W(8->16)+relu -> emb ----------------
__global__ __launch_bounds__(256) void k_gemm_agg(const unsigned short* __restrict__ A,
                                                  const unsigned short* __restrict__ B,
                                                  const float* __restrict__ W,
                                                  const float* __restrict__ bias,
                                                  unsigned short* __restrict__ emb) {
  __shared__ float smem[64 * 129];
  __shared__ float Wsm[F_IN * HGC];
  __shared__ float bsm[HGC];
  unsigned short* As = (unsigned short*)smem;
  unsigned short* Bs = As + 4096;
  int t = threadIdx.x;
  if (t < F_IN * HGC) Wsm[t] = W[t];
  if (t < HGC) bsm[t] = bias[t];
  int m0 = blockIdx.x * 128, n0 = blockIdx.y * 128;
  int wave = t >> 6, lane = t & 63;
  int mh = (wave >> 1) * 64, nh = (wave & 1) * 64;
  int lrow = t >> 2, lslot = t & 3;
  f32x4 acc[4][4];
#pragma unroll
  for (int a = 0; a < 4; ++a)
#pragma unroll
    for (int b = 0; b < 4; ++b) acc[a][b] = (f32x4){0.f, 0.f, 0.f, 0.f};
  const unsigned short* ga0 = A + (size_t)(m0 + lrow) * 512 + lslot * 8;
  const unsigned short* ga1 = A + (size_t)(m0 + 64 + lrow) * 512 + lslot * 8;
  const unsigned short* gb0 = B + (size_t)(n0 + lrow) * 512 + lslot * 8;
  const unsigned short* gb1 = B + (size_t)(n0 + 64 + lrow) * 512 + lslot * 8;
  int rl = lane & 15, ks = lane >> 4;
  for (int kt = 0; kt < 16; ++kt) {
    int k0 = kt * 32;
    gl_lds16(ga0 + k0, &As[t * 8]);
    gl_lds16(ga1 + k0, &As[2048 + t * 8]);
    gl_lds16(gb0 + k0, &Bs[t * 8]);
    gl_lds16(gb1 + k0, &Bs[2048 + t * 8]);
    __syncthreads();
    short8 af[4], bfr[4];
#pragma unroll
    for (int mf = 0; mf < 4; ++mf) af[mf] = *(const short8*)&As[(mh + mf * 16 + rl) * 32 + ks * 8];
#pragma unroll
    for (int nf = 0; nf < 4; ++nf) bfr[nf] = *(const short8*)&Bs[(nh + nf * 16 + rl) * 32 + ks * 8];
#pragma unroll
    for (int mf = 0; mf < 4; ++mf)
#pragma unroll
      for (int nf = 0; nf < 4; ++nf)
        acc[mf][nf] = __builtin_amdgcn_mfma_f32_16x16x32_bf16(af[mf], bfr[nf], acc[mf][nf], 0, 0, 0);
    __syncthreads();
  }
  int rg = lane >> 4;
  for (int p = 0; p < 2; ++p) {
    if ((wave >> 1) == p) {
#pragma unroll
      for (int mf = 0; mf < 4; ++mf)
#pragma unroll
        for (int nf = 0; nf < 4; ++nf)
#pragma unroll
          for (int q = 0; q < 4; ++q)
            smem[(mf * 16 + rg * 4 + q) * 129 + nh + nf * 16 + rl] = acc[mf][nf][q];
    }
    __syncthreads();
    int gl = t >> 5, sub = t & 31;
    int g = blockIdx.x * 16 + p * 8 + gl;
#pragma unroll
    for (int j = 0; j < 4; ++j) {
      int nl = sub + 32 * j, ng = n0 + nl;
      if (ng < N_NODES) {
        float v[8];
#pragma unroll
        for (int f = 0; f < 8; ++f) v[f] = smem[(gl * 8 + f) * 129 + nl];
        short8 o0, o1;
#pragma unroll
        for (int c = 0; c < 8; ++c) {
          float s0 = bsm[c], s1 = bsm[c + 8];
#pragma unroll
          for (int f = 0; f < 8; ++f) {
            s0 += v[f] * Wsm[f * 16 + c];
            s1 += v[f] * Wsm[f * 16 + c + 8];
          }
          o0[c] = (short)f2bf(fmaxf(s0, 0.f));
          o1[c] = (short)f2bf(fmaxf(s1, 0.f));
        }
        unsigned short* dst = emb + (size_t)g * NH + ng * 16;
        *(short8*)dst = o0;
        *(short8*)(dst + 8) = o1;
      }
    }
    __syncthreads();
  }
}

// ---------------- big encoder GEMM: gi = emb(2048x8000) . Wih(1536x8000)^T ----------------
// 128x128 tiles (R5-proven structure), grid (16,12). Writes scan layout giP2.
__global__ __launch_bounds__(256) void k_gemm_enc(
    const unsigned short* __restrict__ A, const unsigned short* __restrict__ Bm,
    float* __restrict__ giP2) {
  __shared__ unsigned short As[128 * 32];
  __shared__ unsigned short Bs[128 * 32];
  int t = threadIdx.x;
  int m0 = blockIdx.x * 128, n0 = blockIdx.y * 128;
  int wave = t >> 6, lane = t & 63;
  int mh = (wave >> 1) * 64, nh = (wave & 1) * 64;
  int lrow = t >> 2, lslot = t & 3;
  f32x4 acc[4][4];
#pragma unroll
  for (int a = 0; a < 4; ++a)
#pragma unroll
    for (int b = 0; b < 4; ++b) acc[a][b] = (f32x4){0.f, 0.f, 0.f, 0.f};
  const unsigned short* ga0 = A + (size_t)(m0 + lrow) * NH + lslot * 8;
  const unsigned short* ga1 = A + (size_t)(m0 + 64 + lrow) * NH + lslot * 8;
  const unsigned short* gb0 = Bm + (size_t)(n0 + lrow) * NH + lslot * 8;
  const unsigned short* gb1 = Bm + (size_t)(n0 + 64 + lrow) * NH + lslot * 8;
  int rl = lane & 15, ks = lane >> 4;
  for (int kt = 0; kt < 250; ++kt) {
    int k0 = kt * 32;
    gl_lds16(ga0 + k0, &As[t * 8]);
    gl_lds16(ga1 + k0, &As[2048 + t * 8]);
    gl_lds16(gb0 + k0, &Bs[t * 8]);
    gl_lds16(gb1 + k0, &Bs[2048 + t * 8]);
    __syncthreads();
    short8 af[4], bfr[4];
#pragma unroll
    for (int mf = 0; mf < 4; ++mf) af[mf] = *(const short8*)&As[(mh + mf * 16 + rl) * 32 + ks * 8];
#pragma unroll
    for (int nf = 0; nf < 4; ++nf) bfr[nf] = *(const short8*)&Bs[(nh + nf * 16 + rl) * 32 + ks * 8];
#pragma unroll
    for (int mf = 0; mf < 4; ++mf)
#pragma unroll
      for (int nf = 0; nf < 4; ++nf)
        acc[mf][nf] = __builtin_amdgcn_mfma_f32_16x16x32_bf16(af[mf], bfr[nf], acc[mf][nf], 0, 0, 0);
    __syncthreads();
  }
  int rg = lane >> 4;
  int gate = n0 >> 9;   // 128-tile never crosses a 512 boundary
#pragma unroll
  for (int mf = 0; mf < 4; ++mf)
#pragma unroll
    for (int nf = 0; nf < 4; ++nf) {
      int n = n0 + nh + nf * 16 + rl;
      int d = n & 511, blk = d >> 5, cc = d & 31;
#pragma unroll
      for (int q = 0; q < 4; ++q) {
        int m = m0 + mh + mf * 16 + rg * 4 + q;
        int s = m & 63, bb = m >> 6;
        giP2[(size_t)(s * 16 + blk) * 3072 + gate * 1024 + bb * 32 + cc] = acc[mf][nf][q];
      }
    }
}

// ---------------- stage h into XOR-swizzled LDS ----------------
__device__ __forceinline__ void stage_hb(const unsigned short* __restrict__ src,
                                         unsigned short* hb, int t) {
  int bw = t >> 3, i8 = t & 7;
  short8 v[8];
#pragma unroll
  for (int i = 0; i < 8; ++i)
    v[i] = *(const short8*)((const char*)src + bw * 1024 + i8 * 128 + i * 16);
#pragma unroll
  for (int i = 0; i < 8; ++i) {
    int kb = i8 * 128 + i * 16;
    *(short8*)((char*)hb + bw * 1024 + (kb ^ ((bw & 15) << 4))) = v[i];
  }
}

__device__ __forceinline__ void gru_core_g(const unsigned short* __restrict__ whhB,
                                           const unsigned short* hb, float* gh,
                                           int t, int c0) {
  int lane = t & 63, g = t >> 6;
  int b31 = lane & 31, kg = lane >> 5;
  if (g < 3) {
    f32x16 acc;
#pragma unroll
    for (int q = 0; q < 16; ++q) acc[q] = 0.f;
    const unsigned short* brow = whhB + (size_t)(g * 512 + c0 + b31) * 512 + kg * 8;
    int asw = (b31 & 15) << 4;
#pragma unroll 4
    for (int kk = 0; kk < 32; ++kk) {
      int kb = (kk * 32 + kg * 16) ^ asw;
      short8 a = *(const short8*)((const char*)hb + b31 * 1024 + kb);
      short8 b = *(const short8*)(brow + kk * 16);
      acc = __builtin_amdgcn_mfma_f32_32x32x16_bf16(a, b, acc, 0, 0, 0);
    }
#pragma unroll
    for (int q = 0; q < 16; ++q) {
      int br = (q & 3) + 8 * (q >> 2) + 4 * kg;
      gh[g * 1024 + br * 32 + b31] = acc[q];
    }
  }
}

__device__ __forceinline__ void gru_gates(const float* gi, const float* gh,
                                          const float* __restrict__ bih,
                                          const float* __restrict__ bhh,
                                          float* __restrict__ hF,
                                          unsigned short* __restrict__ hb_out,
                                          int t, int c0) {
  for (int i = t; i < 1024; i += 256) {
    int b = i >> 5, cc = i & 31, d = c0 + cc;
    float gr = gi[i] + bih[d];
    float gz = gi[1024 + i] + bih[512 + d];
    float gn = gi[2048 + i] + bih[1024 + d];
    float hr = gh[b * 32 + cc] + bhh[d];
    float hz = gh[1024 + b * 32 + cc] + bhh[512 + d];
    float hn = gh[2048 + b * 32 + cc] + bhh[1024 + d];
    float r = sigm(gr + hr), z = sigm(gz + hz);
    float nn = tanhf(gn + r * hn);
    float hp = hF[b * 512 + d];
    float hnew = (1.f - z) * nn + z * hp;
    hF[b * 512 + d] = hnew;
    hb_out[b * 512 + d] = f2bf(hnew);
  }
}

// ---------------- persistent encoder scan (R5/R9 structure, measured ~350us) ----------------
__global__ __launch_bounds__(256, 1) void k_enc_scan(
    const unsigned short* __restrict__ whhB, const float* __restrict__ giP2,
    const float* __restrict__ bih, const float* __restrict__ bhh,
    float* __restrict__ hF, unsigned short* __restrict__ hbA,
    unsigned short* __restrict__ hbB, int* __restrict__ arr) {
  __shared__ unsigned short hb[32 * 512];
  __shared__ float gh[3 * 1024];
  __shared__ float h32[1024];
  __shared__ float gi_lds[3072];
  int t = threadIdx.x, bid = blockIdx.x;
  int c0 = bid * 32;
  int lane = t & 63, g = t >> 6;
  int b31 = lane & 31, kg = lane >> 5;

  short8 wreg[32];
  if (g < 3) {
    const unsigned short* brow = whhB + (size_t)(g * 512 + c0 + b31) * 512 + kg * 8;
#pragma unroll
    for (int kk = 0; kk < 32; ++kk) wreg[kk] = *(const short8*)(brow + kk * 16);
  }
  for (int i = t; i < 1024; i += 256) h32[i] = 0.f;
  int cc = t & 31, d = c0 + cc;
  float bi_r = bih[d], bi_z = bih[512 + d], bi_n = bih[1024 + d];
  float bh_r = bhh[d], bh_z = bhh[512 + d], bh_n = bhh[1024 + d];
  int asw = (b31 & 15) << 4;
  {
    const float* src0 = giP2 + (size_t)bid * 3072;
#pragma unroll
    for (int i = 0; i < 3; ++i)
      gl_lds16(src0 + i * 1024 + t * 4, &gi_lds[i * 1024 + t * 4]);
  }
  __syncthreads();

  for (int s = 0; s < T_STEPS; ++s) {
    const unsigned short* hbin = (s & 1) ? hbB : hbA;
    unsigned short* hbout = (s & 1) ? hbA : hbB;
    if (s > 0 && t < 64) {
      for (;;) {
        int v = __hip_atomic_load(&arr[t & 15], __ATOMIC_ACQUIRE, __HIP_MEMORY_SCOPE_AGENT);
        if (__all(v >= s)) break;
        __builtin_amdgcn_s_sleep(1);
      }
    }
    __syncthreads();
    stage_hb(hbin, hb, t);
    __syncthreads();
    if (g < 3) {
      f32x16 acc0, acc1;
#pragma unroll
      for (int q = 0; q < 16; ++q) { acc0[q] = 0.f; acc1[q] = 0.f; }
      const char* abase = (const char*)hb + b31 * 1024;
#pragma unroll
      for (int kk = 0; kk < 32; ++kk) {
        int kb = (kk * 32 + kg * 16) ^ asw;
        short8 a = *(const short8*)(abase + kb);
        if (kk & 1) acc1 = __builtin_amdgcn_mfma_f32_32x32x16_bf16(a, wreg[kk], acc1, 0, 0, 0);
        else acc0 = __builtin_amdgcn_mfma_f32_32x32x16_bf16(a, wreg[kk], acc0, 0, 0, 0);
      }
#pragma unroll
      for (int q = 0; q < 16; ++q) {
        int br = (q & 3) + 8 * (q >> 2) + 4 * kg;
        gh[g * 1024 + br * 32 + b31] = acc0[q] + acc1[q];
      }
    }
    __syncthreads();
#pragma unroll
    for (int j = 0; j < 4; ++j) {
      int i = t + 256 * j;
      int b = (t >> 5) + 8 * j;
      float r = sigm(gi_lds[i] + bi_r + gh[i] + bh_r);
      float z = sigm(gi_lds[1024 + i] + bi_z + gh[1024 + i] + bh_z);
      float nn = tanhf(gi_lds[2048 + i] + bi_n + r * (gh[2048 + i] + bh_n));
      float hnew = (1.f - z) * nn + z * h32[i];
      h32[i] = hnew;
      hbout[b * 512 + d] = f2bf(hnew);
    }
    __syncthreads();
    if (g == 3 && s + 1 < T_STEPS) {
      const float* srcn = giP2 + (size_t)((s + 1) * 16 + bid) * 3072;
#pragma unroll
      for (int i = 0; i < 12; ++i)
        gl_lds16(srcn + (i * 64 + lane) * 4, &gi_lds[(i * 64 + lane) * 4]);
    }
    if (t == 0) {
      __threadfence();
      __hip_atomic_store(&arr[bid], s + 1, __ATOMIC_RELEASE, __HIP_MEMORY_SCOPE_AGENT);
    }
  }
#pragma unroll
  for (int j = 0; j < 4; ++j) {
    int i = t + 256 * j;
    int b = (t >> 5) + 8 * j;
    hF[b * 512 + d] = h32[i];
  }
}

// ---------------- fused decoder step: P1 gemm (480 blk) -> P2 GRU (blk 0..15) -> P3 fc+agg (blk 0..31) ----------------
// Small-subset polls only: 16 blocks poll 480 P1 flags; 32 blocks poll 16 GRU flags.
// Non-role blocks exit after P1 (frees CUs; pollers(<=32) << 256 CUs => no scheduling deadlock).
__global__ __launch_bounds__(256, 1) void k_dec_step(
    const unsigned short* __restrict__ wihDp, const unsigned short* __restrict__ whhB,
    const float* __restrict__ bih, const float* __restrict__ bhh,
    const float* __restrict__ fcW, const float* __restrict__ fcb,
    const float* __restrict__ Wd, const float* __restrict__ bd,
    const int* __restrict__ rowptr, const int* __restrict__ colA, const float* __restrict__ nrmA,
    unsigned short* __restrict__ E8, float* __restrict__ parts,
    float* __restrict__ hF, const unsigned short* __restrict__ hb_in,
    unsigned short* __restrict__ hb_out, float* __restrict__ out,
    int* __restrict__ fP1, int* __restrict__ fGRU, int s) {
  __shared__ __align__(16) char smem[57344];
  int bid = blockIdx.x, t = threadIdx.x;
  int w = t >> 6, lane = t & 63;
  int b31 = lane & 31, kg = lane >> 5;

  // ---- P1: parts(ntile,kc) = E8 . Wih_slice^T (weights LDS-staged, 4-wave) ----
  {
    unsigned short* wlds = (unsigned short*)smem;
    int ntile = bid / DKC, kc = bid - ntile * DKC;
    const unsigned short* src = wihDp + (size_t)bid * 25600;
    for (int i = w; i < 50; i += 4)
      gl_lds16(src + i * 512 + lane * 8, (char*)wlds + i * 1024 + lane * 16);
    __syncthreads();  // drains staging
    if (w == 0) {
      f32x16 acc0, acc1;
#pragma unroll
      for (int q = 0; q < 16; ++q) { acc0[q] = 0.f; acc1[q] = 0.f; }
      const unsigned short* ea = E8 + (size_t)b31 * NH + kc * 800 + kg * 8;
      const char* wb = (const char*)wlds + kg * 512 + b31 * 16;
#pragma unroll 5
      for (int nd = 0; nd < 50; nd += 2) {
        short8 a0 = *(const short8*)(ea + nd * 16);
        short8 b0 = *(const short8*)(wb + (size_t)nd * 1024);
        short8 a1 = *(const short8*)(ea + (nd + 1) * 16);
        short8 b1 = *(const short8*)(wb + (size_t)(nd + 1) * 1024);
        acc0 = __builtin_amdgcn_mfma_f32_32x32x16_bf16(a0, b0, acc0, 0, 0, 0);
        acc1 = __builtin_amdgcn_mfma_f32_32x32x16_bf16(a1, b1, acc1, 0, 0, 0);
      }
      float* pp = parts + (size_t)(kc * DNT + ntile) * 1024 + b31;
#pragma unroll
      for (int q = 0; q < 16; ++q) {
        int br = (q & 3) + 8 * (q >> 2) + 4 * kg;
        pp[br * 32] = acc0[q] + acc1[q];
      }
    }
    __syncthreads();  // all stores issued before publish
    if (t == 0) {
      __threadfence();
      __hip_atomic_store(&fP1[bid], s + 1, __ATOMIC_RELEASE, __HIP_MEMORY_SCOPE_AGENT);
    }
  }
  if (bid >= NB) return;

  // ---- P2: GRU (blocks 0..15) ----
  if (bid < 16) {
    if (t < 64) {
      for (;;) {
        bool ok = true;
#pragma unroll
        for (int i = 0; i < 8; ++i) {
          int idx = t + (i << 6);
          if (idx < DBLK)
            ok &= (__hip_atomic_load(&fP1[idx], __ATOMIC_RELAXED, __HIP_MEMORY_SCOPE_AGENT) >= s + 1);
        }
        if (__all(ok)) break;
        __builtin_amdgcn_s_sleep(2);
      }
      __threadfence();
    }
    __syncthreads();
    unsigned short* hb = (unsigned short*)smem;
    float* gh = (float*)(smem + 32768);
    float* gi = (float*)(smem + 45056);
    int c0 = bid * 32;
    stage_hb(hb_in, hb, t);
    for (int i = t; i < 3072; i += 256) {
      int gg = i >> 10, r = i & 1023, bb = r >> 5, cc2 = r & 31;
      float a = 0.f;
#pragma unroll
      for (int kc2 = 0; kc2 < DKC; ++kc2)
        a += parts[((size_t)kc2 * DNT + gg * 16 + bid) * 1024 + bb * 32 + cc2];
      gi[i] = a;
    }
    __syncthreads();
    gru_core_g(whhB, hb, gh, t, c0);
    __syncthreads();
    gru_gates(gi, gh, bih, bhh, hF, hb_out, t, c0);
    __syncthreads();
    if (t == 0) {
      __threadfence();
      __hip_atomic_store(&fGRU[bid], s + 1, __ATOMIC_RELEASE, __HIP_MEMORY_SCOPE_AGENT);
    }
  }

  // ---- P3: fc + out + E8 for next step (blocks 0..31) ----
  {
    if (t < 64) {
      for (;;) {
        int f = __hip_atomic_load(&fGRU[t & 15], __ATOMIC_RELAXED, __HIP_MEMORY_SCOPE_AGENT);
        if (__all(f >= s + 1)) break;
        __builtin_amdgcn_s_sleep(1);
      }
      __threadfence();
    }
    __syncthreads();
    float* hrow = (float*)smem;            // 2 KB
    float* orow = (float*)(smem + 2048);   // 2 KB
    float* wds = (float*)(smem + 4352);
    float* bds = (float*)(smem + 4480);
    int b = bid;
    hrow[t] = hF[b * 512 + t];
    if (t < 256) hrow[t + 256] = hF[b * 512 + t + 256];
    if (t < HGC) { wds[t] = Wd[t]; bds[t] = bd[t]; }
    __syncthreads();
    for (int n = t; n < N_NODES; n += 256) {
      const float4* wr = (const float4*)(fcW + (size_t)n * DH);
      float a = 0.f;
#pragma unroll 4
      for (int k = 0; k < 128; ++k) {
        float4 wv = wr[k];
        const float4 hv = *(const float4*)&hrow[k * 4];
        a += wv.x * hv.x + wv.y * hv.y + wv.z * hv.z + wv.w * hv.w;
      }
      float o = a + fcb[n];
      orow[n] = o;
      out[(size_t)b * (DSTEPS * N_NODES) + s * N_NODES + n] = o;
    }
    __syncthreads();
    for (int n = t; n < N_NODES; n += 256) {
      int e1 = rowptr[n + 1];
      float a = 0.f;
      for (int e = rowptr[n]; e < e1; ++e) a += nrmA[e] * orow[colA[e]];
      short8 lo, hi;
#pragma unroll
      for (int c = 0; c < 8; ++c) {
        lo[c] = (short)f2bf(fmaxf(a * wds[c] + bds[c], 0.f));
        hi[c] = (short)f2bf(fmaxf(a * wds[c + 8] + bds[c + 8], 0.f));
      }
      unsigned short* dst = E8 + (size_t)b * NH + n * 16;
      *(short8*)dst = lo;
      *(short8*)(dst + 8) = hi;
    }
  }
}

// ---------------- initial E8 from decoder_initial_input ----------------
__global__ __launch_bounds__(256) void k_agg0(
    const float* __restrict__ dec0, const float* __restrict__ Wd, const float* __restrict__ bd,
    const int* __restrict__ rowptr, const int* __restrict__ col, const float* __restrict__ nrm,
    unsigned short* __restrict__ E8) {
  __shared__ float irow[N_NODES];
  __shared__ float wds[HGC], bds[HGC];
  int b = blockIdx.x, t = threadIdx.x;
  for (int n = t; n < N_NODES; n += 256) irow[n] = dec0[b * N_NODES + n];
  if (t < HGC) { wds[t] = Wd[t]; bds[t] = bd[t]; }
  __syncthreads();
  for (int n = t; n < N_NODES; n += 256) {
    int e1 = rowptr[n + 1];
    float a = 0.f;
    for (int e = rowptr[n]; e < e1; ++e) a += nrm[e] * irow[col[e]];
    short8 lo, hi;
#pragma unroll
    for (int c = 0; c < 8; ++c) {
      lo[c] = (short)f2bf(fmaxf(a * wds[c] + bds[c], 0.f));
      hi[c] = (short)f2bf(fmaxf(a * wds[c + 8] + bds[c + 8], 0.f));
    }
    unsigned short* dst = E8 + (size_t)b * NH + n * 16;
    *(short8*)dst = lo;
    *(short8*)(dst + 8) = hi;
  }
}

extern "C" void kernel_launch(void* const* d_in, const int* in_sizes, int n_in,
                              void* d_out, int out_size, void* d_ws, size_t ws_size,
                              hipStream_t stream) {
  const float* x = (const float*)d_in[0];
  const float* dec0 = (const float*)d_in[1];
  const int* ei = (const int*)d_in[2];
  const float* gWe = (const float*)d_in[3];
  const float* gbe = (const float*)d_in[4];
  const float* gWd = (const float*)d_in[5];
  const float* gbd = (const float*)d_in[6];
  const float* eWih = (const float*)d_in[7];
  const float* eWhh = (const float*)d_in[8];
  const float* ebih = (const float*)d_in[9];
  const float* ebhh = (const float*)d_in[10];
  const float* dWih = (const float*)d_in[11];
  const float* dWhh = (const float*)d_in[12];
  const float* dbih = (const float*)d_in[13];
  const float* dbhh = (const float*)d_in[14];
  const float* fcW = (const float*)d_in[15];
  const float* fcb = (const float*)d_in[16];
  float* out = (float*)d_out;
  (void)in_sizes; (void)n_in; (void)out_size; (void)ws_size;

  char* w = (char*)d_ws;
  size_t off = 0;
  auto alloc = [&](size_t bytes) -> void* {
    void* p = w + off;
    off = (off + bytes + 255) & ~(size_t)255;
    return p;
  };
  int* rowptr = (int*)alloc(512 * 4);
  int* colA = (int*)alloc(E_TOT * 4);
  float* nrmA = (float*)alloc(E_TOT * 4);
  unsigned short* whhE = (unsigned short*)alloc((size_t)G3 * DH * 2);
  unsigned short* whhD = (unsigned short*)alloc((size_t)G3 * DH * 2);
  unsigned short* AhatD = (unsigned short*)alloc(512 * 512 * 2);
  float* hF = (float*)alloc(NB * DH * 4);                     // | contiguous:
  unsigned short* hbX = (unsigned short*)alloc(NB * DH * 2);  // | one memset
  int* arr = (int*)alloc(256);                                // |
  int* fP1 = (int*)alloc(DBLK * 4);                           // |
  int* fGRU = (int*)alloc(256);                               // |
  unsigned short* hbY = (unsigned short*)alloc(NB * DH * 2);
  unsigned short* E8 = (unsigned short*)alloc((size_t)NB * NH * 2);
  unsigned short* emb = (unsigned short*)alloc((size_t)BT * NH * 2);
  char* wihE_parts = (char*)alloc((size_t)G3 * NH * 2);   // wihE, later parts
  unsigned short* wihE = (unsigned short*)wihE_parts;
  float* parts = (float*)wihE_parts;
  unsigned short* wihDp = (unsigned short*)alloc((size_t)DBLK * 25600 * 2);
  char* xT2_giP = (char*)alloc((size_t)16384 * 512 * 2);  // xT2, later giP2
  unsigned short* xT2 = (unsigned short*)xT2_giP;
  float* giP2 = (float*)xT2_giP;

  // zero hF + hbX + arr + fP1 + fGRU (contiguous)
  hipMemsetAsync(hF, 0, NB * DH * 4 + NB * DH * 2 + 256 + DBLK * 4 + 256 + 512, stream);

  k_graph<<<1, 512, 0, stream>>>(ei, rowptr, colA, nrmA);

  int n4w = G3 * NH / 4;
  int n4h = G3 * DH / 4;
  k_f2bf_all<<<(n4w + 2 * n4h + 255) / 256, 256, 0, stream>>>(
      eWih, wihE, n4w, eWhh, whhE, n4h, dWhh, whhD, n4h);
  k_repack<<<3000, 256, 0, stream>>>(dWih, wihDp);

  k_transpose<<<BT, 256, 0, stream>>>(x, xT2);
  k_densify<<<512, 256, 0, stream>>>(rowptr, colA, nrmA, AhatD);
  k_gemm_agg<<<dim3(128, 4), 256, 0, stream>>>(xT2, AhatD, gWe, gbe, emb);

  k_gemm_enc<<<dim3(BT / 128, G3 / 128), 256, 0, stream>>>(emb, wihE, giP2);

  k_enc_scan<<<16, 256, 0, stream>>>(whhE, giP2, ebih, ebhh, hF, hbX, hbY, arr);

  k_agg0<<<NB, 256, 0, stream>>>(dec0, gWd, gbd, rowptr, colA, nrmA, E8);

  for (int s = 0; s < DSTEPS; ++s) {
    const unsigned short* hbin = (s & 1) ? hbY : hbX;
    unsigned short* hbout = (s & 1) ? hbX : hbY;
    k_dec_step<<<DBLK, 256, 0, stream>>>(wihDp, whhD, dbih, dbhh, fcW, fcb, gWd, gbd,
                                         rowptr, colA, nrmA, E8, parts, hF, hbin, hbout,
                                         out, fP1, fGRU, s);
  }
}

// Round 11
// 1923.197 us; speedup vs baseline: 1.1284x; 1.1284x over previous
//
#include <hip/hip_runtime.h>
#include <stdint.h>

typedef short short8 __attribute__((ext_vector_type(8)));
typedef float f32x4 __attribute__((ext_vector_type(4)));
typedef float f32x16 __attribute__((ext_vector_type(16)));

#define N_NODES 500
#define HGC 16
#define DH 512
#define T_STEPS 64
#define NB 32
#define F_IN 8
#define DSTEPS 16
#define E_EDGES 16000
#define E_TOT 16500
#define NH 8000          // N*HG
#define G3 1536          // 3*D
#define BT 2048          // B*T
#define DKC 10           // decoder K-split (800 K each = 50 nodes)
#define DNT 48           // decoder ntiles (32 cols each)
#define DBLK 480         // 48 x 10 blocks

__device__ __forceinline__ unsigned short f2bf(float x) {
  unsigned int u = __float_as_uint(x);
  u = (u + 0x7fffu + ((u >> 16) & 1u)) >> 16;
  return (unsigned short)u;
}

__device__ __forceinline__ void gl_lds16(const void* g, void* l) {
  __builtin_amdgcn_global_load_lds((const __attribute__((address_space(1))) void*)g,
                                   (__attribute__((address_space(3))) void*)l, 16, 0, 0);
}

__device__ __forceinline__ float sigm(float x) { return 1.f / (1.f + __expf(-x)); }

// ---------------- fused graph prep (1 block, 512 threads) ----------------
__global__ __launch_bounds__(512) void k_graph(const int* __restrict__ ei,
                                               int* __restrict__ rowptr,
                                               int* __restrict__ colg, float* __restrict__ nrmg) {
  __shared__ int degL[512];
  __shared__ int scanL[512];
  __shared__ int curL[512];
  __shared__ float dinvL[512];
  int t = threadIdx.x;
  degL[t] = (t < N_NODES) ? 1 : 0;
  __syncthreads();
  for (int e = t; e < E_EDGES; e += 512) atomicAdd(&degL[ei[E_EDGES + e]], 1);
  __syncthreads();
  int v = degL[t];
  scanL[t] = v;
  __syncthreads();
  for (int off = 1; off < 512; off <<= 1) {
    int add = (t >= off) ? scanL[t - off] : 0;
    __syncthreads();
    scanL[t] += add;
    __syncthreads();
  }
  int excl = scanL[t] - v;
  if (t < N_NODES) {
    rowptr[t] = excl;
    curL[t] = excl;
    dinvL[t] = rsqrtf((float)v);
  }
  if (t == 0) rowptr[N_NODES] = scanL[511];
  __syncthreads();
  for (int e = t; e < E_TOT; e += 512) {
    int s_, d_;
    if (e < E_EDGES) { s_ = ei[e]; d_ = ei[E_EDGES + e]; }
    else { s_ = d_ = e - E_EDGES; }
    int pos = atomicAdd(&curL[d_], 1);
    colg[pos] = s_;
    nrmg[pos] = dinvL[s_] * dinvL[d_];
  }
}

// ---------------- merged f32 -> bf16 bulk convert (3 tensors) ----------------
__global__ void k_f2bf_all(const float* __restrict__ a, unsigned short* __restrict__ da, int n4a,
                           const float* __restrict__ b, unsigned short* __restrict__ db, int n4b,
                           const float* __restrict__ c, unsigned short* __restrict__ dc, int n4c) {
  int i = blockIdx.x * blockDim.x + threadIdx.x;
  const float* s;
  unsigned short* d;
  int j = i;
  if (j < n4a) { s = a; d = da; }
  else {
    j -= n4a;
    if (j < n4b) { s = b; d = db; }
    else {
      j -= n4b;
      if (j >= n4c) return;
      s = c; d = dc;
    }
  }
  float4 v = ((const float4*)s)[j];
  ushort4 o;
  o.x = f2bf(v.x); o.y = f2bf(v.y); o.z = f2bf(v.z); o.w = f2bf(v.w);
  ((ushort4*)d)[j] = o;
}

// ---------------- repack dWih f32 -> per-block blobs (bf16), layout [nd][kg][col][8] ----------------
__global__ __launch_bounds__(256) void k_repack(const float* __restrict__ dWih,
                                                unsigned short* __restrict__ wihDp) {
  int i = blockIdx.x * 256 + threadIdx.x;   // 768000 total
  if (i >= DBLK * 50 * 32) return;
  int blob = i / 1600, r = i - blob * 1600;
  int nd = r >> 5, col = r & 31;
  int ntile = blob / DKC, kc = blob - ntile * DKC;
  const float* src = dWih + (size_t)(ntile * 32 + col) * NH + kc * 800 + nd * 16;
  short8 lo, hi;
#pragma unroll
  for (int c = 0; c < 8; ++c) {
    lo[c] = (short)f2bf(src[c]);
    hi[c] = (short)f2bf(src[c + 8]);
  }
  unsigned short* dst = wihDp + (size_t)blob * 25600 + nd * 512 + col * 8;
  *(short8*)dst = lo;
  *(short8*)(dst + 256) = hi;
}

// ---------------- x (2048,500,8) f32 -> xT2 (16384, 512) bf16 (zero-padded cols) ----------------
__global__ __launch_bounds__(256) void k_transpose(const float* __restrict__ x,
                                                   unsigned short* __restrict__ xT2) {
  __shared__ float xs[N_NODES * 9];
  int g = blockIdx.x, t = threadIdx.x;
  const float4* xg = (const float4*)(x + (size_t)g * (N_NODES * F_IN));
  for (int i = t; i < N_NODES * 2; i += 256) {
    float4 v = xg[i];
    int n = i >> 1, fh = (i & 1) * 4;
    float* d = &xs[n * 9 + fh];
    d[0] = v.x; d[1] = v.y; d[2] = v.z; d[3] = v.w;
  }
  __syncthreads();
  int f = t >> 5, u = t & 31;
  short8 lo, hi;
#pragma unroll
  for (int j = 0; j < 8; ++j) {
    int n0 = u * 16 + j, n1 = n0 + 8;
    lo[j] = (short)((n0 < N_NODES) ? f2bf(xs[n0 * 9 + f]) : 0);
    hi[j] = (short)((n1 < N_NODES) ? f2bf(xs[n1 * 9 + f]) : 0);
  }
  unsigned short* dst = xT2 + (size_t)(g * 8 + f) * 512 + u * 16;
  *(short8*)dst = lo;
  *(short8*)(dst + 8) = hi;
}

// ---------------- densify Ahat rows (by dst) -> (512, 512) bf16 ----------------
__global__ __launch_bounds__(256) void k_densify(const int* __restrict__ rowptr,
                                                 const int* __restrict__ col,
                                                 const float* __restrict__ nrm,
                                                 unsigned short* __restrict__ AhatD) {
  __shared__ float row[512];
  int n = blockIdx.x, t = threadIdx.x;
  row[t] = 0.f; row[t + 256] = 0.f;
  __syncthreads();
  if (n < N_NODES) {
    int e1 = rowptr[n + 1];
    for (int e = rowptr[n] + t; e < e1; e += 256) atomicAdd(&row[col[e]], nrm[e]);
  }
  __syncthreads();
  AhatD[n * 512 + t] = f2bf(row[t]);
  AhatD[n * 512 + t + 256] = f2bf(row[t + 256]);
}

// ---------------- agg GEMM: C(16384 gf, 512 n) = xT2 . AhatD^T ; fused W(8->16)+relu -> emb ----------------
__global__ __launch_bounds__(256) void k_gemm_agg(const unsigned short* __restrict__ A,
                                                  const unsigned short* __restrict__ B,
                                                  const float* __restrict__ W,
                                                  const float* __restrict__ bias,
                                                  unsigned short* __restrict__ emb) {
  __shared__ float smem[64 * 129];
  __shared__ float Wsm[F_IN * HGC];
  __shared__ float bsm[HGC];
  unsigned short* As = (unsigned short*)smem;
  unsigned short* Bs = As + 4096;
  int t = threadIdx.x;
  if (t < F_IN * HGC) Wsm[t] = W[t];
  if (t < HGC) bsm[t] = bias[t];
  int m0 = blockIdx.x * 128, n0 = blockIdx.y * 128;
  int wave = t >> 6, lane = t & 63;
  int mh = (wave >> 1) * 64, nh = (wave & 1) * 64;
  int lrow = t >> 2, lslot = t & 3;
  f32x4 acc[4][4];
#pragma unroll
  for (int a = 0; a < 4; ++a)
#pragma unroll
    for (int b = 0; b < 4; ++b) acc[a][b] = (f32x4){0.f, 0.f, 0.f, 0.f};
  const unsigned short* ga0 = A + (size_t)(m0 + lrow) * 512 + lslot * 8;
  const unsigned short* ga1 = A + (size_t)(m0 + 64 + lrow) * 512 + lslot * 8;
  const unsigned short* gb0 = B + (size_t)(n0 + lrow) * 512 + lslot * 8;
  const unsigned short* gb1 = B + (size_t)(n0 + 64 + lrow) * 512 + lslot * 8;
  int rl = lane & 15, ks = lane >> 4;
  for (int kt = 0; kt < 16; ++kt) {
    int k0 = kt * 32;
    gl_lds16(ga0 + k0, &As[t * 8]);
    gl_lds16(ga1 + k0, &As[2048 + t * 8]);
    gl_lds16(gb0 + k0, &Bs[t * 8]);
    gl_lds16(gb1 + k0, &Bs[2048 + t * 8]);
    __syncthreads();
    short8 af[4], bfr[4];
#pragma unroll
    for (int mf = 0; mf < 4; ++mf) af[mf] = *(const short8*)&As[(mh + mf * 16 + rl) * 32 + ks * 8];
#pragma unroll
    for (int nf = 0; nf < 4; ++nf) bfr[nf] = *(const short8*)&Bs[(nh + nf * 16 + rl) * 32 + ks * 8];
#pragma unroll
    for (int mf = 0; mf < 4; ++mf)
#pragma unroll
      for (int nf = 0; nf < 4; ++nf)
        acc[mf][nf] = __builtin_amdgcn_mfma_f32_16x16x32_bf16(af[mf], bfr[nf], acc[mf][nf], 0, 0, 0);
    __syncthreads();
  }
  int rg = lane >> 4;
  for (int p = 0; p < 2; ++p) {
    if ((wave >> 1) == p) {
#pragma unroll
      for (int mf = 0; mf < 4; ++mf)
#pragma unroll
        for (int nf = 0; nf < 4; ++nf)
#pragma unroll
          for (int q = 0; q < 4; ++q)
            smem[(mf * 16 + rg * 4 + q) * 129 + nh + nf * 16 + rl] = acc[mf][nf][q];
    }
    __syncthreads();
    int gl = t >> 5, sub = t & 31;
    int g = blockIdx.x * 16 + p * 8 + gl;
#pragma unroll
    for (int j = 0; j < 4; ++j) {
      int nl = sub + 32 * j, ng = n0 + nl;
      if (ng < N_NODES) {
        float v[8];
#pragma unroll
        for (int f = 0; f < 8; ++f) v[f] = smem[(gl * 8 + f) * 129 + nl];
        short8 o0, o1;
#pragma unroll
        for (int c = 0; c < 8; ++c) {
          float s0 = bsm[c], s1 = bsm[c + 8];
#pragma unroll
          for (int f = 0; f < 8; ++f) {
            s0 += v[f] * Wsm[f * 16 + c];
            s1 += v[f] * Wsm[f * 16 + c + 8];
          }
          o0[c] = (short)f2bf(fmaxf(s0, 0.f));
          o1[c] = (short)f2bf(fmaxf(s1, 0.f));
        }
        unsigned short* dst = emb + (size_t)g * NH + ng * 16;
        *(short8*)dst = o0;
        *(short8*)(dst + 8) = o1;
      }
    }
    __syncthreads();
  }
}

// ---------------- big encoder GEMM: gi = emb(2048x8000) . Wih(1536x8000)^T ----------------
// 128x128 tiles, grid (16,12). Writes scan layout giP2.
__global__ __launch_bounds__(256) void k_gemm_enc(
    const unsigned short* __restrict__ A, const unsigned short* __restrict__ Bm,
    float* __restrict__ giP2) {
  __shared__ unsigned short As[128 * 32];
  __shared__ unsigned short Bs[128 * 32];
  int t = threadIdx.x;
  int m0 = blockIdx.x * 128, n0 = blockIdx.y * 128;
  int wave = t >> 6, lane = t & 63;
  int mh = (wave >> 1) * 64, nh = (wave & 1) * 64;
  int lrow = t >> 2, lslot = t & 3;
  f32x4 acc[4][4];
#pragma unroll
  for (int a = 0; a < 4; ++a)
#pragma unroll
    for (int b = 0; b < 4; ++b) acc[a][b] = (f32x4){0.f, 0.f, 0.f, 0.f};
  const unsigned short* ga0 = A + (size_t)(m0 + lrow) * NH + lslot * 8;
  const unsigned short* ga1 = A + (size_t)(m0 + 64 + lrow) * NH + lslot * 8;
  const unsigned short* gb0 = Bm + (size_t)(n0 + lrow) * NH + lslot * 8;
  const unsigned short* gb1 = Bm + (size_t)(n0 + 64 + lrow) * NH + lslot * 8;
  int rl = lane & 15, ks = lane >> 4;
  for (int kt = 0; kt < 250; ++kt) {
    int k0 = kt * 32;
    gl_lds16(ga0 + k0, &As[t * 8]);
    gl_lds16(ga1 + k0, &As[2048 + t * 8]);
    gl_lds16(gb0 + k0, &Bs[t * 8]);
    gl_lds16(gb1 + k0, &Bs[2048 + t * 8]);
    __syncthreads();
    short8 af[4], bfr[4];
#pragma unroll
    for (int mf = 0; mf < 4; ++mf) af[mf] = *(const short8*)&As[(mh + mf * 16 + rl) * 32 + ks * 8];
#pragma unroll
    for (int nf = 0; nf < 4; ++nf) bfr[nf] = *(const short8*)&Bs[(nh + nf * 16 + rl) * 32 + ks * 8];
#pragma unroll
    for (int mf = 0; mf < 4; ++mf)
#pragma unroll
      for (int nf = 0; nf < 4; ++nf)
        acc[mf][nf] = __builtin_amdgcn_mfma_f32_16x16x32_bf16(af[mf], bfr[nf], acc[mf][nf], 0, 0, 0);
    __syncthreads();
  }
  int rg = lane >> 4;
  int gate = n0 >> 9;   // 128-tile never crosses a 512 boundary
#pragma unroll
  for (int mf = 0; mf < 4; ++mf)
#pragma unroll
    for (int nf = 0; nf < 4; ++nf) {
      int n = n0 + nh + nf * 16 + rl;
      int d = n & 511, blk = d >> 5, cc = d & 31;
#pragma unroll
      for (int q = 0; q < 4; ++q) {
        int m = m0 + mh + mf * 16 + rg * 4 + q;
        int s = m & 63, bb = m >> 6;
        giP2[(size_t)(s * 16 + blk) * 3072 + gate * 1024 + bb * 32 + cc] = acc[mf][nf][q];
      }
    }
}

// ---------------- stage h into XOR-swizzled LDS ----------------
__device__ __forceinline__ void stage_hb(const unsigned short* __restrict__ src,
                                         unsigned short* hb, int t) {
  int bw = t >> 3, i8 = t & 7;
  short8 v[8];
#pragma unroll
  for (int i = 0; i < 8; ++i)
    v[i] = *(const short8*)((const char*)src + bw * 1024 + i8 * 128 + i * 16);
#pragma unroll
  for (int i = 0; i < 8; ++i) {
    int kb = i8 * 128 + i * 16;
    *(short8*)((char*)hb + bw * 1024 + (kb ^ ((bw & 15) << 4))) = v[i];
  }
}

__device__ __forceinline__ void gru_core_g(const unsigned short* __restrict__ whhB,
                                           const unsigned short* hb, float* gh,
                                           int t, int c0) {
  int lane = t & 63, g = t >> 6;
  int b31 = lane & 31, kg = lane >> 5;
  if (g < 3) {
    f32x16 acc;
#pragma unroll
    for (int q = 0; q < 16; ++q) acc[q] = 0.f;
    const unsigned short* brow = whhB + (size_t)(g * 512 + c0 + b31) * 512 + kg * 8;
    int asw = (b31 & 15) << 4;
#pragma unroll 4
    for (int kk = 0; kk < 32; ++kk) {
      int kb = (kk * 32 + kg * 16) ^ asw;
      short8 a = *(const short8*)((const char*)hb + b31 * 1024 + kb);
      short8 b = *(const short8*)(brow + kk * 16);
      acc = __builtin_amdgcn_mfma_f32_32x32x16_bf16(a, b, acc, 0, 0, 0);
    }
#pragma unroll
    for (int q = 0; q < 16; ++q) {
      int br = (q & 3) + 8 * (q >> 2) + 4 * kg;
      gh[g * 1024 + br * 32 + b31] = acc[q];
    }
  }
}

__device__ __forceinline__ void gru_gates(const float* gi, const float* gh,
                                          const float* __restrict__ bih,
                                          const float* __restrict__ bhh,
                                          float* __restrict__ hF,
                                          unsigned short* __restrict__ hb_out,
                                          int t, int c0) {
  for (int i = t; i < 1024; i += 256) {
    int b = i >> 5, cc = i & 31, d = c0 + cc;
    float gr = gi[i] + bih[d];
    float gz = gi[1024 + i] + bih[512 + d];
    float gn = gi[2048 + i] + bih[1024 + d];
    float hr = gh[b * 32 + cc] + bhh[d];
    float hz = gh[1024 + b * 32 + cc] + bhh[512 + d];
    float hn = gh[2048 + b * 32 + cc] + bhh[1024 + d];
    float r = sigm(gr + hr), z = sigm(gz + hz);
    float nn = tanhf(gn + r * hn);
    float hp = hF[b * 512 + d];
    float hnew = (1.f - z) * nn + z * hp;
    hF[b * 512 + d] = hnew;
    hb_out[b * 512 + d] = f2bf(hnew);
  }
}

// ---------------- persistent encoder scan (R5/R9 structure, measured ~350us) ----------------
__global__ __launch_bounds__(256, 1) void k_enc_scan(
    const unsigned short* __restrict__ whhB, const float* __restrict__ giP2,
    const float* __restrict__ bih, const float* __restrict__ bhh,
    float* __restrict__ hF, unsigned short* __restrict__ hbA,
    unsigned short* __restrict__ hbB, int* __restrict__ arr) {
  __shared__ unsigned short hb[32 * 512];
  __shared__ float gh[3 * 1024];
  __shared__ float h32[1024];
  __shared__ float gi_lds[3072];
  int t = threadIdx.x, bid = blockIdx.x;
  int c0 = bid * 32;
  int lane = t & 63, g = t >> 6;
  int b31 = lane & 31, kg = lane >> 5;

  short8 wreg[32];
  if (g < 3) {
    const unsigned short* brow = whhB + (size_t)(g * 512 + c0 + b31) * 512 + kg * 8;
#pragma unroll
    for (int kk = 0; kk < 32; ++kk) wreg[kk] = *(const short8*)(brow + kk * 16);
  }
  for (int i = t; i < 1024; i += 256) h32[i] = 0.f;
  int cc = t & 31, d = c0 + cc;
  float bi_r = bih[d], bi_z = bih[512 + d], bi_n = bih[1024 + d];
  float bh_r = bhh[d], bh_z = bhh[512 + d], bh_n = bhh[1024 + d];
  int asw = (b31 & 15) << 4;
  {
    const float* src0 = giP2 + (size_t)bid * 3072;
#pragma unroll
    for (int i = 0; i < 3; ++i)
      gl_lds16(src0 + i * 1024 + t * 4, &gi_lds[i * 1024 + t * 4]);
  }
  __syncthreads();

  for (int s = 0; s < T_STEPS; ++s) {
    const unsigned short* hbin = (s & 1) ? hbB : hbA;
    unsigned short* hbout = (s & 1) ? hbA : hbB;
    if (s > 0 && t < 64) {
      for (;;) {
        int v = __hip_atomic_load(&arr[t & 15], __ATOMIC_ACQUIRE, __HIP_MEMORY_SCOPE_AGENT);
        if (__all(v >= s)) break;
        __builtin_amdgcn_s_sleep(1);
      }
    }
    __syncthreads();
    stage_hb(hbin, hb, t);
    __syncthreads();
    if (g < 3) {
      f32x16 acc0, acc1;
#pragma unroll
      for (int q = 0; q < 16; ++q) { acc0[q] = 0.f; acc1[q] = 0.f; }
      const char* abase = (const char*)hb + b31 * 1024;
#pragma unroll
      for (int kk = 0; kk < 32; ++kk) {
        int kb = (kk * 32 + kg * 16) ^ asw;
        short8 a = *(const short8*)(abase + kb);
        if (kk & 1) acc1 = __builtin_amdgcn_mfma_f32_32x32x16_bf16(a, wreg[kk], acc1, 0, 0, 0);
        else acc0 = __builtin_amdgcn_mfma_f32_32x32x16_bf16(a, wreg[kk], acc0, 0, 0, 0);
      }
#pragma unroll
      for (int q = 0; q < 16; ++q) {
        int br = (q & 3) + 8 * (q >> 2) + 4 * kg;
        gh[g * 1024 + br * 32 + b31] = acc0[q] + acc1[q];
      }
    }
    __syncthreads();
#pragma unroll
    for (int j = 0; j < 4; ++j) {
      int i = t + 256 * j;
      int b = (t >> 5) + 8 * j;
      float r = sigm(gi_lds[i] + bi_r + gh[i] + bh_r);
      float z = sigm(gi_lds[1024 + i] + bi_z + gh[1024 + i] + bh_z);
      float nn = tanhf(gi_lds[2048 + i] + bi_n + r * (gh[2048 + i] + bh_n));
      float hnew = (1.f - z) * nn + z * h32[i];
      h32[i] = hnew;
      hbout[b * 512 + d] = f2bf(hnew);
    }
    __syncthreads();
    if (g == 3 && s + 1 < T_STEPS) {
      const float* srcn = giP2 + (size_t)((s + 1) * 16 + bid) * 3072;
#pragma unroll
      for (int i = 0; i < 12; ++i)
        gl_lds16(srcn + (i * 64 + lane) * 4, &gi_lds[(i * 64 + lane) * 4]);
    }
    if (t == 0) {
      __threadfence();
      __hip_atomic_store(&arr[bid], s + 1, __ATOMIC_RELEASE, __HIP_MEMORY_SCOPE_AGENT);
    }
  }
#pragma unroll
  for (int j = 0; j < 4; ++j) {
    int i = t + 256 * j;
    int b = (t >> 5) + 8 * j;
    hF[b * 512 + d] = h32[i];
  }
}

// ---------------- decoder gi GEMM (R9 version, proven): LDS-staged weights, pure MFMA ----------------
__global__ __launch_bounds__(64) void k_dec_gemm(
    const unsigned short* __restrict__ wihDp, const unsigned short* __restrict__ E8,
    float* __restrict__ parts) {
  __shared__ unsigned short wlds[25600];  // 51.2 KB
  int bid = blockIdx.x, t = threadIdx.x;
  int b31 = t & 31, kg = t >> 5;
  int ntile = bid / DKC, kc = bid - ntile * DKC;
  const unsigned short* src = wihDp + (size_t)bid * 25600;
#pragma unroll 10
  for (int i = 0; i < 50; ++i)
    gl_lds16(src + i * 512 + t * 8, (char*)wlds + i * 1024 + t * 16);
  __syncthreads();  // one vmcnt drain for all 50 staging loads
  f32x16 acc0, acc1;
#pragma unroll
  for (int q = 0; q < 16; ++q) { acc0[q] = 0.f; acc1[q] = 0.f; }
  const unsigned short* ea = E8 + (size_t)b31 * NH + kc * 800 + kg * 8;
  const char* wb = (const char*)wlds + kg * 512 + b31 * 16;
#pragma unroll 5
  for (int nd = 0; nd < 50; nd += 2) {
    short8 a0 = *(const short8*)(ea + nd * 16);
    short8 b0 = *(const short8*)(wb + (size_t)nd * 1024);
    short8 a1 = *(const short8*)(ea + (nd + 1) * 16);
    short8 b1 = *(const short8*)(wb + (size_t)(nd + 1) * 1024);
    acc0 = __builtin_amdgcn_mfma_f32_32x32x16_bf16(a0, b0, acc0, 0, 0, 0);
    acc1 = __builtin_amdgcn_mfma_f32_32x32x16_bf16(a1, b1, acc1, 0, 0, 0);
  }
  float* pp = parts + (size_t)(kc * DNT + ntile) * 1024 + b31;
#pragma unroll
  for (int q = 0; q < 16; ++q) {
    int br = (q & 3) + 8 * (q >> 2) + 4 * kg;
    pp[br * 32] = acc0[q] + acc1[q];
  }
}

// ---------------- merged GRU + fc + agg + E8 (16 blocks, enc_scan-class internal barrier) ----------------
__global__ __launch_bounds__(256, 1) void k_gru_fc(
    const unsigned short* __restrict__ whhB, const float* __restrict__ parts,
    const float* __restrict__ bih, const float* __restrict__ bhh,
    float* __restrict__ hF, const unsigned short* __restrict__ hb_in,
    unsigned short* __restrict__ hb_out,
    const float* __restrict__ fcW, const float* __restrict__ fcb,
    const float* __restrict__ Wd, const float* __restrict__ bd,
    const int* __restrict__ rowptr, const int* __restrict__ colA, const float* __restrict__ nrmA,
    float* __restrict__ out, unsigned short* __restrict__ E8,
    int* __restrict__ fGRU, int s) {
  __shared__ unsigned short hb[32 * 512];  // 32 KB; reused as hrow/orow in phase B
  __shared__ float gh[3 * 1024];
  __shared__ float gi[3 * 1024];
  int t = threadIdx.x, bid = blockIdx.x;
  int c0 = bid * 32;
  // ---- phase A: GRU ----
  stage_hb(hb_in, hb, t);
  for (int i = t; i < 3072; i += 256) {
    int gg = i >> 10, r = i & 1023, bb = r >> 5, cc2 = r & 31;
    float a = 0.f;
#pragma unroll
    for (int kc = 0; kc < DKC; ++kc)
      a += parts[((size_t)kc * DNT + gg * 16 + bid) * 1024 + bb * 32 + cc2];
    gi[i] = a;
  }
  __syncthreads();
  gru_core_g(whhB, hb, gh, t, c0);
  __syncthreads();
  gru_gates(gi, gh, bih, bhh, hF, hb_out, t, c0);
  // ---- 16-block barrier (proven pattern) ----
  __syncthreads();
  if (t == 0) {
    __threadfence();
    __hip_atomic_store(&fGRU[bid], s + 1, __ATOMIC_RELEASE, __HIP_MEMORY_SCOPE_AGENT);
  }
  if (t < 64) {
    for (;;) {
      int f = __hip_atomic_load(&fGRU[t & 15], __ATOMIC_ACQUIRE, __HIP_MEMORY_SCOPE_AGENT);
      if (__all(f >= s + 1)) break;
      __builtin_amdgcn_s_sleep(1);
    }
  }
  __syncthreads();
  // ---- phase B: fc + out + agg + E8 for batches 2*bid, 2*bid+1 ----
  float* hrow = (float*)hb;            // [2][512]
  float* orow = (float*)hb + 1024;     // [2][512]
  float* wds = gh;                     // 16
  float* bds = gh + 16;                // 16
  int b0 = bid * 2;
  for (int i = t; i < 1024; i += 256) {
    int bb = i >> 9, dd = i & 511;
    hrow[i] = hF[(b0 + bb) * 512 + dd];
  }
  if (t < HGC) { wds[t] = Wd[t]; bds[t] = bd[t]; }
  __syncthreads();
  for (int n = t; n < N_NODES; n += 256) {
    const float4* wr = (const float4*)(fcW + (size_t)n * DH);
    float a0 = 0.f, a1 = 0.f;
#pragma unroll 4
    for (int k = 0; k < 128; ++k) {
      float4 wv = wr[k];
      float4 h0 = *(const float4*)&hrow[k * 4];
      float4 h1 = *(const float4*)&hrow[512 + k * 4];
      a0 += wv.x * h0.x + wv.y * h0.y + wv.z * h0.z + wv.w * h0.w;
      a1 += wv.x * h1.x + wv.y * h1.y + wv.z * h1.z + wv.w * h1.w;
    }
    float fb = fcb[n];
    float o0 = a0 + fb, o1 = a1 + fb;
    orow[n] = o0;
    orow[512 + n] = o1;
    out[(size_t)b0 * (DSTEPS * N_NODES) + s * N_NODES + n] = o0;
    out[(size_t)(b0 + 1) * (DSTEPS * N_NODES) + s * N_NODES + n] = o1;
  }
  __syncthreads();
  for (int n = t; n < N_NODES; n += 256) {
    int e1 = rowptr[n + 1];
    float a0 = 0.f, a1 = 0.f;
    for (int e = rowptr[n]; e < e1; ++e) {
      int c = colA[e];
      float wv = nrmA[e];
      a0 += wv * orow[c];
      a1 += wv * orow[512 + c];
    }
    short8 l0, h0v, l1, h1v;
#pragma unroll
    for (int c = 0; c < 8; ++c) {
      l0[c] = (short)f2bf(fmaxf(a0 * wds[c] + bds[c], 0.f));
      h0v[c] = (short)f2bf(fmaxf(a0 * wds[c + 8] + bds[c + 8], 0.f));
      l1[c] = (short)f2bf(fmaxf(a1 * wds[c] + bds[c], 0.f));
      h1v[c] = (short)f2bf(fmaxf(a1 * wds[c + 8] + bds[c + 8], 0.f));
    }
    unsigned short* d0 = E8 + (size_t)b0 * NH + n * 16;
    unsigned short* d1 = E8 + (size_t)(b0 + 1) * NH + n * 16;
    *(short8*)d0 = l0;
    *(short8*)(d0 + 8) = h0v;
    *(short8*)d1 = l1;
    *(short8*)(d1 + 8) = h1v;
  }
}

// ---------------- initial E8 from decoder_initial_input ----------------
__global__ __launch_bounds__(256) void k_agg0(
    const float* __restrict__ dec0, const float* __restrict__ Wd, const float* __restrict__ bd,
    const int* __restrict__ rowptr, const int* __restrict__ col, const float* __restrict__ nrm,
    unsigned short* __restrict__ E8) {
  __shared__ float irow[N_NODES];
  __shared__ float wds[HGC], bds[HGC];
  int b = blockIdx.x, t = threadIdx.x;
  for (int n = t; n < N_NODES; n += 256) irow[n] = dec0[b * N_NODES + n];
  if (t < HGC) { wds[t] = Wd[t]; bds[t] = bd[t]; }
  __syncthreads();
  for (int n = t; n < N_NODES; n += 256) {
    int e1 = rowptr[n + 1];
    float a = 0.f;
    for (int e = rowptr[n]; e < e1; ++e) a += nrm[e] * irow[col[e]];
    short8 lo, hi;
#pragma unroll
    for (int c = 0; c < 8; ++c) {
      lo[c] = (short)f2bf(fmaxf(a * wds[c] + bds[c], 0.f));
      hi[c] = (short)f2bf(fmaxf(a * wds[c + 8] + bds[c + 8], 0.f));
    }
    unsigned short* dst = E8 + (size_t)b * NH + n * 16;
    *(short8*)dst = lo;
    *(short8*)(dst + 8) = hi;
  }
}

extern "C" void kernel_launch(void* const* d_in, const int* in_sizes, int n_in,
                              void* d_out, int out_size, void* d_ws, size_t ws_size,
                              hipStream_t stream) {
  const float* x = (const float*)d_in[0];
  const float* dec0 = (const float*)d_in[1];
  const int* ei = (const int*)d_in[2];
  const float* gWe = (const float*)d_in[3];
  const float* gbe = (const float*)d_in[4];
  const float* gWd = (const float*)d_in[5];
  const float* gbd = (const float*)d_in[6];
  const float* eWih = (const float*)d_in[7];
  const float* eWhh = (const float*)d_in[8];
  const float* ebih = (const float*)d_in[9];
  const float* ebhh = (const float*)d_in[10];
  const float* dWih = (const float*)d_in[11];
  const float* dWhh = (const float*)d_in[12];
  const float* dbih = (const float*)d_in[13];
  const float* dbhh = (const float*)d_in[14];
  const float* fcW = (const float*)d_in[15];
  const float* fcb = (const float*)d_in[16];
  float* out = (float*)d_out;
  (void)in_sizes; (void)n_in; (void)out_size; (void)ws_size;

  char* w = (char*)d_ws;
  size_t off = 0;
  auto alloc = [&](size_t bytes) -> void* {
    void* p = w + off;
    off = (off + bytes + 255) & ~(size_t)255;
    return p;
  };
  int* rowptr = (int*)alloc(512 * 4);
  int* colA = (int*)alloc(E_TOT * 4);
  float* nrmA = (float*)alloc(E_TOT * 4);
  unsigned short* whhE = (unsigned short*)alloc((size_t)G3 * DH * 2);
  unsigned short* whhD = (unsigned short*)alloc((size_t)G3 * DH * 2);
  unsigned short* AhatD = (unsigned short*)alloc(512 * 512 * 2);
  float* hF = (float*)alloc(NB * DH * 4);                     // | contiguous:
  unsigned short* hbX = (unsigned short*)alloc(NB * DH * 2);  // | one memset
  int* arr = (int*)alloc(256);                                // |
  int* fGRU = (int*)alloc(256);                               // |
  unsigned short* hbY = (unsigned short*)alloc(NB * DH * 2);
  unsigned short* E8 = (unsigned short*)alloc((size_t)NB * NH * 2);
  unsigned short* emb = (unsigned short*)alloc((size_t)BT * NH * 2);
  char* wihE_parts = (char*)alloc((size_t)G3 * NH * 2);   // wihE, later parts
  unsigned short* wihE = (unsigned short*)wihE_parts;
  float* parts = (float*)wihE_parts;
  unsigned short* wihDp = (unsigned short*)alloc((size_t)DBLK * 25600 * 2);
  char* xT2_giP = (char*)alloc((size_t)16384 * 512 * 2);  // xT2, later giP2
  unsigned short* xT2 = (unsigned short*)xT2_giP;
  float* giP2 = (float*)xT2_giP;

  // zero hF + hbX + arr + fGRU (contiguous)
  hipMemsetAsync(hF, 0, NB * DH * 4 + NB * DH * 2 + 256 + 256, stream);

  k_graph<<<1, 512, 0, stream>>>(ei, rowptr, colA, nrmA);

  int n4w = G3 * NH / 4;
  int n4h = G3 * DH / 4;
  k_f2bf_all<<<(n4w + 2 * n4h + 255) / 256, 256, 0, stream>>>(
      eWih, wihE, n4w, eWhh, whhE, n4h, dWhh, whhD, n4h);
  k_repack<<<3000, 256, 0, stream>>>(dWih, wihDp);

  k_transpose<<<BT, 256, 0, stream>>>(x, xT2);
  k_densify<<<512, 256, 0, stream>>>(rowptr, colA, nrmA, AhatD);
  k_gemm_agg<<<dim3(128, 4), 256, 0, stream>>>(xT2, AhatD, gWe, gbe, emb);

  k_gemm_enc<<<dim3(BT / 128, G3 / 128), 256, 0, stream>>>(emb, wihE, giP2);

  k_enc_scan<<<16, 256, 0, stream>>>(whhE, giP2, ebih, ebhh, hF, hbX, hbY, arr);

  k_agg0<<<NB, 256, 0, stream>>>(dec0, gWd, gbd, rowptr, colA, nrmA, E8);

  for (int s = 0; s < DSTEPS; ++s) {
    const unsigned short* hbin = (s & 1) ? hbY : hbX;
    unsigned short* hbout = (s & 1) ? hbX : hbY;
    k_dec_gemm<<<DBLK, 64, 0, stream>>>(wihDp, E8, parts);
    k_gru_fc<<<16, 256, 0, stream>>>(whhD, parts, dbih, dbhh, hF, hbin, hbout,
                                     fcW, fcb, gWd, gbd, rowptr, colA, nrmA,
                                     out, E8, fGRU, s);
  }
}

// Round 12
// 1481.582 us; speedup vs baseline: 1.4647x; 1.2981x over previous
//
#include <hip/hip_runtime.h>
#include <stdint.h>

typedef short short8 __attribute__((ext_vector_type(8)));
typedef float f32x4 __attribute__((ext_vector_type(4)));
typedef float f32x16 __attribute__((ext_vector_type(16)));

#define N_NODES 500
#define HGC 16
#define DH 512
#define T_STEPS 64
#define NB 32
#define F_IN 8
#define DSTEPS 16
#define E_EDGES 16000
#define E_TOT 16500
#define NH 8000          // N*HG
#define G3 1536          // 3*D
#define BT 2048          // B*T
#define DKC 10           // decoder K-split (800 K each = 50 nodes)
#define DNT 48           // decoder ntiles (32 cols each)
#define DBLK 480         // 48 x 10 blocks

__device__ __forceinline__ unsigned short f2bf(float x) {
  unsigned int u = __float_as_uint(x);
  u = (u + 0x7fffu + ((u >> 16) & 1u)) >> 16;
  return (unsigned short)u;
}

__device__ __forceinline__ void gl_lds16(const void* g, void* l) {
  __builtin_amdgcn_global_load_lds((const __attribute__((address_space(1))) void*)g,
                                   (__attribute__((address_space(3))) void*)l, 16, 0, 0);
}

__device__ __forceinline__ float sigm(float x) { return 1.f / (1.f + __expf(-x)); }

// ---------------- fused graph prep (1 block, 512 threads) ----------------
__global__ __launch_bounds__(512) void k_graph(const int* __restrict__ ei,
                                               int* __restrict__ rowptr,
                                               int* __restrict__ colg, float* __restrict__ nrmg) {
  __shared__ int degL[512];
  __shared__ int scanL[512];
  __shared__ int curL[512];
  __shared__ float dinvL[512];
  int t = threadIdx.x;
  degL[t] = (t < N_NODES) ? 1 : 0;
  __syncthreads();
  for (int e = t; e < E_EDGES; e += 512) atomicAdd(&degL[ei[E_EDGES + e]], 1);
  __syncthreads();
  int v = degL[t];
  scanL[t] = v;
  __syncthreads();
  for (int off = 1; off < 512; off <<= 1) {
    int add = (t >= off) ? scanL[t - off] : 0;
    __syncthreads();
    scanL[t] += add;
    __syncthreads();
  }
  int excl = scanL[t] - v;
  if (t < N_NODES) {
    rowptr[t] = excl;
    curL[t] = excl;
    dinvL[t] = rsqrtf((float)v);
  }
  if (t == 0) rowptr[N_NODES] = scanL[511];
  __syncthreads();
  for (int e = t; e < E_TOT; e += 512) {
    int s_, d_;
    if (e < E_EDGES) { s_ = ei[e]; d_ = ei[E_EDGES + e]; }
    else { s_ = d_ = e - E_EDGES; }
    int pos = atomicAdd(&curL[d_], 1);
    colg[pos] = s_;
    nrmg[pos] = dinvL[s_] * dinvL[d_];
  }
}

// ---------------- merged f32 -> bf16 bulk convert (3 tensors) ----------------
__global__ void k_f2bf_all(const float* __restrict__ a, unsigned short* __restrict__ da, int n4a,
                           const float* __restrict__ b, unsigned short* __restrict__ db, int n4b,
                           const float* __restrict__ c, unsigned short* __restrict__ dc, int n4c) {
  int i = blockIdx.x * blockDim.x + threadIdx.x;
  const float* s;
  unsigned short* d;
  int j = i;
  if (j < n4a) { s = a; d = da; }
  else {
    j -= n4a;
    if (j < n4b) { s = b; d = db; }
    else {
      j -= n4b;
      if (j >= n4c) return;
      s = c; d = dc;
    }
  }
  float4 v = ((const float4*)s)[j];
  ushort4 o;
  o.x = f2bf(v.x); o.y = f2bf(v.y); o.z = f2bf(v.z); o.w = f2bf(v.w);
  ((ushort4*)d)[j] = o;
}

// ---------------- fcW (500x512 f32) -> fcWb (512x512 bf16, zero-padded rows) ----------------
__global__ void k_f2bf_fc(const float* __restrict__ fcW, unsigned short* __restrict__ fcWb) {
  int i = blockIdx.x * 256 + threadIdx.x;  // 65536 quads
  if (i >= 512 * 512 / 4) return;
  int row = i >> 7;
  ushort4 o = {0, 0, 0, 0};
  if (row < N_NODES) {
    float4 v = ((const float4*)fcW)[i];
    o.x = f2bf(v.x); o.y = f2bf(v.y); o.z = f2bf(v.z); o.w = f2bf(v.w);
  }
  ((ushort4*)fcWb)[i] = o;
}

// ---------------- repack dWih f32 -> per-block blobs (bf16), layout [nd][kg][col][8] ----------------
__global__ __launch_bounds__(256) void k_repack(const float* __restrict__ dWih,
                                                unsigned short* __restrict__ wihDp) {
  int i = blockIdx.x * 256 + threadIdx.x;   // 768000 total
  if (i >= DBLK * 50 * 32) return;
  int blob = i / 1600, r = i - blob * 1600;
  int nd = r >> 5, col = r & 31;
  int ntile = blob / DKC, kc = blob - ntile * DKC;
  const float* src = dWih + (size_t)(ntile * 32 + col) * NH + kc * 800 + nd * 16;
  short8 lo, hi;
#pragma unroll
  for (int c = 0; c < 8; ++c) {
    lo[c] = (short)f2bf(src[c]);
    hi[c] = (short)f2bf(src[c + 8]);
  }
  unsigned short* dst = wihDp + (size_t)blob * 25600 + nd * 512 + col * 8;
  *(short8*)dst = lo;
  *(short8*)(dst + 256) = hi;
}

// ---------------- x (2048,500,8) f32 -> xT2 (16384, 512) bf16 (zero-padded cols) ----------------
__global__ __launch_bounds__(256) void k_transpose(const float* __restrict__ x,
                                                   unsigned short* __restrict__ xT2) {
  __shared__ float xs[N_NODES * 9];
  int g = blockIdx.x, t = threadIdx.x;
  const float4* xg = (const float4*)(x + (size_t)g * (N_NODES * F_IN));
  for (int i = t; i < N_NODES * 2; i += 256) {
    float4 v = xg[i];
    int n = i >> 1, fh = (i & 1) * 4;
    float* d = &xs[n * 9 + fh];
    d[0] = v.x; d[1] = v.y; d[2] = v.z; d[3] = v.w;
  }
  __syncthreads();
  int f = t >> 5, u = t & 31;
  short8 lo, hi;
#pragma unroll
  for (int j = 0; j < 8; ++j) {
    int n0 = u * 16 + j, n1 = n0 + 8;
    lo[j] = (short)((n0 < N_NODES) ? f2bf(xs[n0 * 9 + f]) : 0);
    hi[j] = (short)((n1 < N_NODES) ? f2bf(xs[n1 * 9 + f]) : 0);
  }
  unsigned short* dst = xT2 + (size_t)(g * 8 + f) * 512 + u * 16;
  *(short8*)dst = lo;
  *(short8*)(dst + 8) = hi;
}

// ---------------- densify Ahat rows (by dst) -> (512, 512) bf16 ----------------
__global__ __launch_bounds__(256) void k_densify(const int* __restrict__ rowptr,
                                                 const int* __restrict__ col,
                                                 const float* __restrict__ nrm,
                                                 unsigned short* __restrict__ AhatD) {
  __shared__ float row[512];
  int n = blockIdx.x, t = threadIdx.x;
  row[t] = 0.f; row[t + 256] = 0.f;
  __syncthreads();
  if (n < N_NODES) {
    int e1 = rowptr[n + 1];
    for (int e = rowptr[n] + t; e < e1; e += 256) atomicAdd(&row[col[e]], nrm[e]);
  }
  __syncthreads();
  AhatD[n * 512 + t] = f2bf(row[t]);
  AhatD[n * 512 + t + 256] = f2bf(row[t + 256]);
}

// ---------------- agg GEMM: C(16384 gf, 512 n) = xT2 . AhatD^T ; fused W(8->16)+relu -> emb ----------------
__global__ __launch_bounds__(256) void k_gemm_agg(const unsigned short* __restrict__ A,
                                                  const unsigned short* __restrict__ B,
                                                  const float* __restrict__ W,
                                                  const float* __restrict__ bias,
                                                  unsigned short* __restrict__ emb) {
  __shared__ float smem[64 * 129];
  __shared__ float Wsm[F_IN * HGC];
  __shared__ float bsm[HGC];
  unsigned short* As = (unsigned short*)smem;
  unsigned short* Bs = As + 4096;
  int t = threadIdx.x;
  if (t < F_IN * HGC) Wsm[t] = W[t];
  if (t < HGC) bsm[t] = bias[t];
  int m0 = blockIdx.x * 128, n0 = blockIdx.y * 128;
  int wave = t >> 6, lane = t & 63;
  int mh = (wave >> 1) * 64, nh = (wave & 1) * 64;
  int lrow = t >> 2, lslot = t & 3;
  f32x4 acc[4][4];
#pragma unroll
  for (int a = 0; a < 4; ++a)
#pragma unroll
    for (int b = 0; b < 4; ++b) acc[a][b] = (f32x4){0.f, 0.f, 0.f, 0.f};
  const unsigned short* ga0 = A + (size_t)(m0 + lrow) * 512 + lslot * 8;
  const unsigned short* ga1 = A + (size_t)(m0 + 64 + lrow) * 512 + lslot * 8;
  const unsigned short* gb0 = B + (size_t)(n0 + lrow) * 512 + lslot * 8;
  const unsigned short* gb1 = B + (size_t)(n0 + 64 + lrow) * 512 + lslot * 8;
  int rl = lane & 15, ks = lane >> 4;
  for (int kt = 0; kt < 16; ++kt) {
    int k0 = kt * 32;
    gl_lds16(ga0 + k0, &As[t * 8]);
    gl_lds16(ga1 + k0, &As[2048 + t * 8]);
    gl_lds16(gb0 + k0, &Bs[t * 8]);
    gl_lds16(gb1 + k0, &Bs[2048 + t * 8]);
    __syncthreads();
    short8 af[4], bfr[4];
#pragma unroll
    for (int mf = 0; mf < 4; ++mf) af[mf] = *(const short8*)&As[(mh + mf * 16 + rl) * 32 + ks * 8];
#pragma unroll
    for (int nf = 0; nf < 4; ++nf) bfr[nf] = *(const short8*)&Bs[(nh + nf * 16 + rl) * 32 + ks * 8];
#pragma unroll
    for (int mf = 0; mf < 4; ++mf)
#pragma unroll
      for (int nf = 0; nf < 4; ++nf)
        acc[mf][nf] = __builtin_amdgcn_mfma_f32_16x16x32_bf16(af[mf], bfr[nf], acc[mf][nf], 0, 0, 0);
    __syncthreads();
  }
  int rg = lane >> 4;
  for (int p = 0; p < 2; ++p) {
    if ((wave >> 1) == p) {
#pragma unroll
      for (int mf = 0; mf < 4; ++mf)
#pragma unroll
        for (int nf = 0; nf < 4; ++nf)
#pragma unroll
          for (int q = 0; q < 4; ++q)
            smem[(mf * 16 + rg * 4 + q) * 129 + nh + nf * 16 + rl] = acc[mf][nf][q];
    }
    __syncthreads();
    int gl = t >> 5, sub = t & 31;
    int g = blockIdx.x * 16 + p * 8 + gl;
#pragma unroll
    for (int j = 0; j < 4; ++j) {
      int nl = sub + 32 * j, ng = n0 + nl;
      if (ng < N_NODES) {
        float v[8];
#pragma unroll
        for (int f = 0; f < 8; ++f) v[f] = smem[(gl * 8 + f) * 129 + nl];
        short8 o0, o1;
#pragma unroll
        for (int c = 0; c < 8; ++c) {
          float s0 = bsm[c], s1 = bsm[c + 8];
#pragma unroll
          for (int f = 0; f < 8; ++f) {
            s0 += v[f] * Wsm[f * 16 + c];
            s1 += v[f] * Wsm[f * 16 + c + 8];
          }
          o0[c] = (short)f2bf(fmaxf(s0, 0.f));
          o1[c] = (short)f2bf(fmaxf(s1, 0.f));
        }
        unsigned short* dst = emb + (size_t)g * NH + ng * 16;
        *(short8*)dst = o0;
        *(short8*)(dst + 8) = o1;
      }
    }
    __syncthreads();
  }
}

// ---------------- big encoder GEMM (R9 128x64, grid (16,24)): writes scan layout giP2 ----------------
__global__ __launch_bounds__(256) void k_gemm_enc(
    const unsigned short* __restrict__ A, const unsigned short* __restrict__ Bm,
    float* __restrict__ giP2) {
  __shared__ unsigned short As[128 * 32];
  __shared__ unsigned short Bs[64 * 32];
  int t = threadIdx.x;
  int m0 = blockIdx.x * 128, n0 = blockIdx.y * 64;
  int wave = t >> 6, lane = t & 63;
  int mh = (wave >> 1) * 64, nh = (wave & 1) * 32;
  int lrow = t >> 2, lslot = t & 3;
  f32x4 acc[4][2];
#pragma unroll
  for (int a = 0; a < 4; ++a)
#pragma unroll
    for (int b = 0; b < 2; ++b) acc[a][b] = (f32x4){0.f, 0.f, 0.f, 0.f};
  const unsigned short* ga0 = A + (size_t)(m0 + lrow) * NH + lslot * 8;
  const unsigned short* ga1 = A + (size_t)(m0 + 64 + lrow) * NH + lslot * 8;
  const unsigned short* gb0 = Bm + (size_t)(n0 + lrow) * NH + lslot * 8;
  int rl = lane & 15, ks = lane >> 4;
  for (int kt = 0; kt < 250; ++kt) {
    int k0 = kt * 32;
    gl_lds16(ga0 + k0, &As[t * 8]);
    gl_lds16(ga1 + k0, &As[2048 + t * 8]);
    gl_lds16(gb0 + k0, &Bs[t * 8]);
    __syncthreads();
    short8 af[4], bfr[2];
#pragma unroll
    for (int mf = 0; mf < 4; ++mf) af[mf] = *(const short8*)&As[(mh + mf * 16 + rl) * 32 + ks * 8];
#pragma unroll
    for (int nf = 0; nf < 2; ++nf) bfr[nf] = *(const short8*)&Bs[(nh + nf * 16 + rl) * 32 + ks * 8];
#pragma unroll
    for (int mf = 0; mf < 4; ++mf)
#pragma unroll
      for (int nf = 0; nf < 2; ++nf)
        acc[mf][nf] = __builtin_amdgcn_mfma_f32_16x16x32_bf16(af[mf], bfr[nf], acc[mf][nf], 0, 0, 0);
    __syncthreads();
  }
  int rg = lane >> 4;
  int gate = n0 >> 9;
#pragma unroll
  for (int mf = 0; mf < 4; ++mf)
#pragma unroll
    for (int nf = 0; nf < 2; ++nf) {
      int n = n0 + nh + nf * 16 + rl;
      int d = n & 511, blk = d >> 5, cc = d & 31;
#pragma unroll
      for (int q = 0; q < 4; ++q) {
        int m = m0 + mh + mf * 16 + rg * 4 + q;
        int s = m & 63, bb = m >> 6;
        giP2[(size_t)(s * 16 + blk) * 3072 + gate * 1024 + bb * 32 + cc] = acc[mf][nf][q];
      }
    }
}

// ---------------- stage h into XOR-swizzled LDS ----------------
__device__ __forceinline__ void stage_hb(const unsigned short* __restrict__ src,
                                         unsigned short* hb, int t) {
  int bw = t >> 3, i8 = t & 7;
  short8 v[8];
#pragma unroll
  for (int i = 0; i < 8; ++i)
    v[i] = *(const short8*)((const char*)src + bw * 1024 + i8 * 128 + i * 16);
#pragma unroll
  for (int i = 0; i < 8; ++i) {
    int kb = i8 * 128 + i * 16;
    *(short8*)((char*)hb + bw * 1024 + (kb ^ ((bw & 15) << 4))) = v[i];
  }
}

__device__ __forceinline__ void gru_core_g(const unsigned short* __restrict__ whhB,
                                           const unsigned short* hb, float* gh,
                                           int t, int c0) {
  int lane = t & 63, g = t >> 6;
  int b31 = lane & 31, kg = lane >> 5;
  if (g < 3) {
    f32x16 acc;
#pragma unroll
    for (int q = 0; q < 16; ++q) acc[q] = 0.f;
    const unsigned short* brow = whhB + (size_t)(g * 512 + c0 + b31) * 512 + kg * 8;
    int asw = (b31 & 15) << 4;
#pragma unroll 4
    for (int kk = 0; kk < 32; ++kk) {
      int kb = (kk * 32 + kg * 16) ^ asw;
      short8 a = *(const short8*)((const char*)hb + b31 * 1024 + kb);
      short8 b = *(const short8*)(brow + kk * 16);
      acc = __builtin_amdgcn_mfma_f32_32x32x16_bf16(a, b, acc, 0, 0, 0);
    }
#pragma unroll
    for (int q = 0; q < 16; ++q) {
      int br = (q & 3) + 8 * (q >> 2) + 4 * kg;
      gh[g * 1024 + br * 32 + b31] = acc[q];
    }
  }
}

__device__ __forceinline__ void gru_gates(const float* gi, const float* gh,
                                          const float* __restrict__ bih,
                                          const float* __restrict__ bhh,
                                          float* __restrict__ hF,
                                          unsigned short* __restrict__ hb_out,
                                          int t, int c0) {
  for (int i = t; i < 1024; i += 256) {
    int b = i >> 5, cc = i & 31, d = c0 + cc;
    float gr = gi[i] + bih[d];
    float gz = gi[1024 + i] + bih[512 + d];
    float gn = gi[2048 + i] + bih[1024 + d];
    float hr = gh[b * 32 + cc] + bhh[d];
    float hz = gh[1024 + b * 32 + cc] + bhh[512 + d];
    float hn = gh[2048 + b * 32 + cc] + bhh[1024 + d];
    float r = sigm(gr + hr), z = sigm(gz + hz);
    float nn = tanhf(gn + r * hn);
    float hp = hF[b * 512 + d];
    float hnew = (1.f - z) * nn + z * hp;
    hF[b * 512 + d] = hnew;
    hb_out[b * 512 + d] = f2bf(hnew);
  }
}

// ---------------- persistent encoder scan (R5/R9 structure, measured ~353us) ----------------
__global__ __launch_bounds__(256, 1) void k_enc_scan(
    const unsigned short* __restrict__ whhB, const float* __restrict__ giP2,
    const float* __restrict__ bih, const float* __restrict__ bhh,
    float* __restrict__ hF, unsigned short* __restrict__ hbA,
    unsigned short* __restrict__ hbB, int* __restrict__ arr) {
  __shared__ unsigned short hb[32 * 512];
  __shared__ float gh[3 * 1024];
  __shared__ float h32[1024];
  __shared__ float gi_lds[3072];
  int t = threadIdx.x, bid = blockIdx.x;
  int c0 = bid * 32;
  int lane = t & 63, g = t >> 6;
  int b31 = lane & 31, kg = lane >> 5;

  short8 wreg[32];
  if (g < 3) {
    const unsigned short* brow = whhB + (size_t)(g * 512 + c0 + b31) * 512 + kg * 8;
#pragma unroll
    for (int kk = 0; kk < 32; ++kk) wreg[kk] = *(const short8*)(brow + kk * 16);
  }
  for (int i = t; i < 1024; i += 256) h32[i] = 0.f;
  int cc = t & 31, d = c0 + cc;
  float bi_r = bih[d], bi_z = bih[512 + d], bi_n = bih[1024 + d];
  float bh_r = bhh[d], bh_z = bhh[512 + d], bh_n = bhh[1024 + d];
  int asw = (b31 & 15) << 4;
  {
    const float* src0 = giP2 + (size_t)bid * 3072;
#pragma unroll
    for (int i = 0; i < 3; ++i)
      gl_lds16(src0 + i * 1024 + t * 4, &gi_lds[i * 1024 + t * 4]);
  }
  __syncthreads();

  for (int s = 0; s < T_STEPS; ++s) {
    const unsigned short* hbin = (s & 1) ? hbB : hbA;
    unsigned short* hbout = (s & 1) ? hbA : hbB;
    if (s > 0 && t < 64) {
      for (;;) {
        int v = __hip_atomic_load(&arr[t & 15], __ATOMIC_ACQUIRE, __HIP_MEMORY_SCOPE_AGENT);
        if (__all(v >= s)) break;
        __builtin_amdgcn_s_sleep(1);
      }
    }
    __syncthreads();
    stage_hb(hbin, hb, t);
    __syncthreads();
    if (g < 3) {
      f32x16 acc0, acc1;
#pragma unroll
      for (int q = 0; q < 16; ++q) { acc0[q] = 0.f; acc1[q] = 0.f; }
      const char* abase = (const char*)hb + b31 * 1024;
#pragma unroll
      for (int kk = 0; kk < 32; ++kk) {
        int kb = (kk * 32 + kg * 16) ^ asw;
        short8 a = *(const short8*)(abase + kb);
        if (kk & 1) acc1 = __builtin_amdgcn_mfma_f32_32x32x16_bf16(a, wreg[kk], acc1, 0, 0, 0);
        else acc0 = __builtin_amdgcn_mfma_f32_32x32x16_bf16(a, wreg[kk], acc0, 0, 0, 0);
      }
#pragma unroll
      for (int q = 0; q < 16; ++q) {
        int br = (q & 3) + 8 * (q >> 2) + 4 * kg;
        gh[g * 1024 + br * 32 + b31] = acc0[q] + acc1[q];
      }
    }
    __syncthreads();
#pragma unroll
    for (int j = 0; j < 4; ++j) {
      int i = t + 256 * j;
      int b = (t >> 5) + 8 * j;
      float r = sigm(gi_lds[i] + bi_r + gh[i] + bh_r);
      float z = sigm(gi_lds[1024 + i] + bi_z + gh[1024 + i] + bh_z);
      float nn = tanhf(gi_lds[2048 + i] + bi_n + r * (gh[2048 + i] + bh_n));
      float hnew = (1.f - z) * nn + z * h32[i];
      h32[i] = hnew;
      hbout[b * 512 + d] = f2bf(hnew);
    }
    __syncthreads();
    if (g == 3 && s + 1 < T_STEPS) {
      const float* srcn = giP2 + (size_t)((s + 1) * 16 + bid) * 3072;
#pragma unroll
      for (int i = 0; i < 12; ++i)
        gl_lds16(srcn + (i * 64 + lane) * 4, &gi_lds[(i * 64 + lane) * 4]);
    }
    if (t == 0) {
      __threadfence();
      __hip_atomic_store(&arr[bid], s + 1, __ATOMIC_RELEASE, __HIP_MEMORY_SCOPE_AGENT);
    }
  }
#pragma unroll
  for (int j = 0; j < 4; ++j) {
    int i = t + 256 * j;
    int b = (t >> 5) + 8 * j;
    hF[b * 512 + d] = h32[i];
  }
}

// ---------------- decoder gi GEMM (R9 version, proven): LDS-staged weights, pure MFMA ----------------
__global__ __launch_bounds__(64) void k_dec_gemm(
    const unsigned short* __restrict__ wihDp, const unsigned short* __restrict__ E8,
    float* __restrict__ parts) {
  __shared__ unsigned short wlds[25600];  // 51.2 KB
  int bid = blockIdx.x, t = threadIdx.x;
  int b31 = t & 31, kg = t >> 5;
  int ntile = bid / DKC, kc = bid - ntile * DKC;
  const unsigned short* src = wihDp + (size_t)bid * 25600;
#pragma unroll 10
  for (int i = 0; i < 50; ++i)
    gl_lds16(src + i * 512 + t * 8, (char*)wlds + i * 1024 + t * 16);
  __syncthreads();
  f32x16 acc0, acc1;
#pragma unroll
  for (int q = 0; q < 16; ++q) { acc0[q] = 0.f; acc1[q] = 0.f; }
  const unsigned short* ea = E8 + (size_t)b31 * NH + kc * 800 + kg * 8;
  const char* wb = (const char*)wlds + kg * 512 + b31 * 16;
#pragma unroll 5
  for (int nd = 0; nd < 50; nd += 2) {
    short8 a0 = *(const short8*)(ea + nd * 16);
    short8 b0 = *(const short8*)(wb + (size_t)nd * 1024);
    short8 a1 = *(const short8*)(ea + (nd + 1) * 16);
    short8 b1 = *(const short8*)(wb + (size_t)(nd + 1) * 1024);
    acc0 = __builtin_amdgcn_mfma_f32_32x32x16_bf16(a0, b0, acc0, 0, 0, 0);
    acc1 = __builtin_amdgcn_mfma_f32_32x32x16_bf16(a1, b1, acc1, 0, 0, 0);
  }
  float* pp = parts + (size_t)(kc * DNT + ntile) * 1024 + b31;
#pragma unroll
  for (int q = 0; q < 16; ++q) {
    int br = (q & 3) + 8 * (q >> 2) + 4 * kg;
    pp[br * 32] = acc0[q] + acc1[q];
  }
}

// ---------------- merged GRU + fc(MFMA n-split) + agg + E8 (16 blocks, 2 internal barriers) ----------------
__global__ __launch_bounds__(256, 1) void k_gru_fc(
    const unsigned short* __restrict__ whhB, const float* __restrict__ parts,
    const float* __restrict__ bih, const float* __restrict__ bhh,
    float* __restrict__ hF, const unsigned short* __restrict__ hb_in,
    unsigned short* __restrict__ hb_out,
    const unsigned short* __restrict__ fcWb, const float* __restrict__ fcb,
    const float* __restrict__ Wd, const float* __restrict__ bd,
    const int* __restrict__ rowptr, const int* __restrict__ colA, const float* __restrict__ nrmA,
    float* __restrict__ out, unsigned short* __restrict__ E8,
    int* __restrict__ fGRU, int s) {
  __shared__ unsigned short hb[32 * 512];  // 32 KB
  __shared__ float gh[3 * 1024];           // 12 KB (reused: wds/bds)
  __shared__ float gi[3 * 1024];           // 12 KB (reused: orow[2][512])
  int t = threadIdx.x, bid = blockIdx.x;
  int c0 = bid * 32;
  int lane = t & 63, g = t >> 6;
  int b31 = lane & 31, kg = lane >> 5;
  // ---- phase A: GRU ----
  stage_hb(hb_in, hb, t);
  for (int i = t; i < 3072; i += 256) {
    int gg = i >> 10, r = i & 1023, bb = r >> 5, cc2 = r & 31;
    float a = 0.f;
#pragma unroll
    for (int kc = 0; kc < DKC; ++kc)
      a += parts[((size_t)kc * DNT + gg * 16 + bid) * 1024 + bb * 32 + cc2];
    gi[i] = a;
  }
  __syncthreads();
  gru_core_g(whhB, hb, gh, t, c0);
  __syncthreads();
  gru_gates(gi, gh, bih, bhh, hF, hb_out, t, c0);
  __syncthreads();
  // ---- barrier 1: all hb_out cols written ----
  if (t == 0) {
    __threadfence();
    __hip_atomic_store(&fGRU[bid], 2 * s + 1, __ATOMIC_RELEASE, __HIP_MEMORY_SCOPE_AGENT);
  }
  if (t < 64) {
    for (;;) {
      int f = __hip_atomic_load(&fGRU[t & 15], __ATOMIC_ACQUIRE, __HIP_MEMORY_SCOPE_AGENT);
      if (__all(f >= 2 * s + 1)) break;
      __builtin_amdgcn_s_sleep(1);
    }
  }
  __syncthreads();
  // ---- phase B1: fc via MFMA, node-split (block handles nodes n0..n0+31) ----
  stage_hb(hb_out, hb, t);  // h_new bf16, swizzled
  __syncthreads();
  if (g == 0) {
    f32x16 acc;
#pragma unroll
    for (int q = 0; q < 16; ++q) acc[q] = 0.f;
    int n0 = bid * 32;
    int nrow = n0 + b31;
    const unsigned short* brow = fcWb + (size_t)nrow * 512 + kg * 8;
    const char* abase = (const char*)hb + b31 * 1024;
    int asw = (b31 & 15) << 4;
#pragma unroll 4
    for (int kk = 0; kk < 32; ++kk) {
      int kb = (kk * 32 + kg * 16) ^ asw;
      short8 a = *(const short8*)(abase + kb);
      short8 b = *(const short8*)(brow + kk * 16);
      acc = __builtin_amdgcn_mfma_f32_32x32x16_bf16(a, b, acc, 0, 0, 0);
    }
    if (nrow < N_NODES) {
      float fb = fcb[nrow];
#pragma unroll
      for (int q = 0; q < 16; ++q) {
        int br = (q & 3) + 8 * (q >> 2) + 4 * kg;  // batch
        out[(size_t)br * (DSTEPS * N_NODES) + s * N_NODES + nrow] = acc[q] + fb;
      }
    }
  }
  __syncthreads();
  // ---- barrier 2: all out cols written ----
  if (t == 0) {
    __threadfence();
    __hip_atomic_store(&fGRU[bid], 2 * s + 2, __ATOMIC_RELEASE, __HIP_MEMORY_SCOPE_AGENT);
  }
  if (t < 64) {
    for (;;) {
      int f = __hip_atomic_load(&fGRU[t & 15], __ATOMIC_ACQUIRE, __HIP_MEMORY_SCOPE_AGENT);
      if (__all(f >= 2 * s + 2)) break;
      __builtin_amdgcn_s_sleep(1);
    }
  }
  __syncthreads();
  // ---- phase B2: agg + E8 for batches 2*bid, 2*bid+1 ----
  float* orow = gi;          // [2][512]
  float* wds = gh;           // 16
  float* bds = gh + 16;      // 16
  int b0 = bid * 2;
  for (int i = t; i < 1000; i += 256) {
    int bb = (i >= 500) ? 1 : 0;
    int n = i - bb * 500;
    orow[bb * 512 + n] = out[(size_t)(b0 + bb) * (DSTEPS * N_NODES) + s * N_NODES + n];
  }
  if (t < HGC) { wds[t] = Wd[t]; bds[t] = bd[t]; }
  __syncthreads();
  for (int n = t; n < N_NODES; n += 256) {
    int e1 = rowptr[n + 1];
    float a0 = 0.f, a1 = 0.f;
    for (int e = rowptr[n]; e < e1; ++e) {
      int c = colA[e];
      float wv = nrmA[e];
      a0 += wv * orow[c];
      a1 += wv * orow[512 + c];
    }
    short8 l0, h0v, l1, h1v;
#pragma unroll
    for (int c = 0; c < 8; ++c) {
      l0[c] = (short)f2bf(fmaxf(a0 * wds[c] + bds[c], 0.f));
      h0v[c] = (short)f2bf(fmaxf(a0 * wds[c + 8] + bds[c + 8], 0.f));
      l1[c] = (short)f2bf(fmaxf(a1 * wds[c] + bds[c], 0.f));
      h1v[c] = (short)f2bf(fmaxf(a1 * wds[c + 8] + bds[c + 8], 0.f));
    }
    unsigned short* d0 = E8 + (size_t)b0 * NH + n * 16;
    unsigned short* d1 = E8 + (size_t)(b0 + 1) * NH + n * 16;
    *(short8*)d0 = l0;
    *(short8*)(d0 + 8) = h0v;
    *(short8*)d1 = l1;
    *(short8*)(d1 + 8) = h1v;
  }
}

// ---------------- initial E8 from decoder_initial_input ----------------
__global__ __launch_bounds__(256) void k_agg0(
    const float* __restrict__ dec0, const float* __restrict__ Wd, const float* __restrict__ bd,
    const int* __restrict__ rowptr, const int* __restrict__ col, const float* __restrict__ nrm,
    unsigned short* __restrict__ E8) {
  __shared__ float irow[N_NODES];
  __shared__ float wds[HGC], bds[HGC];
  int b = blockIdx.x, t = threadIdx.x;
  for (int n = t; n < N_NODES; n += 256) irow[n] = dec0[b * N_NODES + n];
  if (t < HGC) { wds[t] = Wd[t]; bds[t] = bd[t]; }
  __syncthreads();
  for (int n = t; n < N_NODES; n += 256) {
    int e1 = rowptr[n + 1];
    float a = 0.f;
    for (int e = rowptr[n]; e < e1; ++e) a += nrm[e] * irow[col[e]];
    short8 lo, hi;
#pragma unroll
    for (int c = 0; c < 8; ++c) {
      lo[c] = (short)f2bf(fmaxf(a * wds[c] + bds[c], 0.f));
      hi[c] = (short)f2bf(fmaxf(a * wds[c + 8] + bds[c + 8], 0.f));
    }
    unsigned short* dst = E8 + (size_t)b * NH + n * 16;
    *(short8*)dst = lo;
    *(short8*)(dst + 8) = hi;
  }
}

extern "C" void kernel_launch(void* const* d_in, const int* in_sizes, int n_in,
                              void* d_out, int out_size, void* d_ws, size_t ws_size,
                              hipStream_t stream) {
  const float* x = (const float*)d_in[0];
  const float* dec0 = (const float*)d_in[1];
  const int* ei = (const int*)d_in[2];
  const float* gWe = (const float*)d_in[3];
  const float* gbe = (const float*)d_in[4];
  const float* gWd = (const float*)d_in[5];
  const float* gbd = (const float*)d_in[6];
  const float* eWih = (const float*)d_in[7];
  const float* eWhh = (const float*)d_in[8];
  const float* ebih = (const float*)d_in[9];
  const float* ebhh = (const float*)d_in[10];
  const float* dWih = (const float*)d_in[11];
  const float* dWhh = (const float*)d_in[12];
  const float* dbih = (const float*)d_in[13];
  const float* dbhh = (const float*)d_in[14];
  const float* fcW = (const float*)d_in[15];
  const float* fcb = (const float*)d_in[16];
  float* out = (float*)d_out;
  (void)in_sizes; (void)n_in; (void)out_size; (void)ws_size;

  char* w = (char*)d_ws;
  size_t off = 0;
  auto alloc = [&](size_t bytes) -> void* {
    void* p = w + off;
    off = (off + bytes + 255) & ~(size_t)255;
    return p;
  };
  int* rowptr = (int*)alloc(512 * 4);
  int* colA = (int*)alloc(E_TOT * 4);
  float* nrmA = (float*)alloc(E_TOT * 4);
  unsigned short* whhE = (unsigned short*)alloc((size_t)G3 * DH * 2);
  unsigned short* whhD = (unsigned short*)alloc((size_t)G3 * DH * 2);
  unsigned short* AhatD = (unsigned short*)alloc(512 * 512 * 2);
  unsigned short* fcWb = (unsigned short*)alloc(512 * 512 * 2);
  float* hF = (float*)alloc(NB * DH * 4);                     // | contiguous:
  unsigned short* hbX = (unsigned short*)alloc(NB * DH * 2);  // | one memset
  int* arr = (int*)alloc(256);                                // |
  int* fGRU = (int*)alloc(256);                               // |
  unsigned short* hbY = (unsigned short*)alloc(NB * DH * 2);
  unsigned short* E8 = (unsigned short*)alloc((size_t)NB * NH * 2);
  unsigned short* emb = (unsigned short*)alloc((size_t)BT * NH * 2);
  char* wihE_parts = (char*)alloc((size_t)G3 * NH * 2);   // wihE, later parts
  unsigned short* wihE = (unsigned short*)wihE_parts;
  float* parts = (float*)wihE_parts;
  unsigned short* wihDp = (unsigned short*)alloc((size_t)DBLK * 25600 * 2);
  char* xT2_giP = (char*)alloc((size_t)16384 * 512 * 2);  // xT2, later giP2
  unsigned short* xT2 = (unsigned short*)xT2_giP;
  float* giP2 = (float*)xT2_giP;

  // zero hF + hbX + arr + fGRU (contiguous)
  hipMemsetAsync(hF, 0, NB * DH * 4 + NB * DH * 2 + 256 + 256, stream);

  k_graph<<<1, 512, 0, stream>>>(ei, rowptr, colA, nrmA);

  int n4w = G3 * NH / 4;
  int n4h = G3 * DH / 4;
  k_f2bf_all<<<(n4w + 2 * n4h + 255) / 256, 256, 0, stream>>>(
      eWih, wihE, n4w, eWhh, whhE, n4h, dWhh, whhD, n4h);
  k_f2bf_fc<<<256, 256, 0, stream>>>(fcW, fcWb);
  k_repack<<<3000, 256, 0, stream>>>(dWih, wihDp);

  k_transpose<<<BT, 256, 0, stream>>>(x, xT2);
  k_densify<<<512, 256, 0, stream>>>(rowptr, colA, nrmA, AhatD);
  k_gemm_agg<<<dim3(128, 4), 256, 0, stream>>>(xT2, AhatD, gWe, gbe, emb);

  k_gemm_enc<<<dim3(BT / 128, G3 / 64), 256, 0, stream>>>(emb, wihE, giP2);

  k_enc_scan<<<16, 256, 0, stream>>>(whhE, giP2, ebih, ebhh, hF, hbX, hbY, arr);

  k_agg0<<<NB, 256, 0, stream>>>(dec0, gWd, gbd, rowptr, colA, nrmA, E8);

  for (int s = 0; s < DSTEPS; ++s) {
    const unsigned short* hbin = (s & 1) ? hbY : hbX;
    unsigned short* hbout = (s & 1) ? hbX : hbY;
    k_dec_gemm<<<DBLK, 64, 0, stream>>>(wihDp, E8, parts);
    k_gru_fc<<<16, 256, 0, stream>>>(whhD, parts, dbih, dbhh, hF, hbin, hbout,
                                     fcWb, fcb, gWd, gbd, rowptr, colA, nrmA,
                                     out, E8, fGRU, s);
  }
}